// Round 1
// baseline (744.714 us; speedup 1.0000x reference)
//
#include <hip/hip_runtime.h>
#include <math.h>

#define HD 128          // hidden dim (= H*C = D_IN)
#define NEG_SLOPE 0.2f
#define EPSV 1e-16f

// ---------------- CSR build ----------------
__global__ void init_counts(int* __restrict__ cnt, int N) {
    int i = blockIdx.x * blockDim.x + threadIdx.x;
    if (i < N) cnt[i] = 1;   // self-loop pre-count
}

__global__ void count_edges(const int* __restrict__ dst, int* __restrict__ cnt, int E) {
    int i = blockIdx.x * blockDim.x + threadIdx.x;
    if (i < E) atomicAdd(&cnt[dst[i]], 1);
}

__global__ __launch_bounds__(1024) void scan_counts(int* __restrict__ cnt,
                                                    int* __restrict__ indptr, int N) {
    __shared__ int sums[1024];
    int t = threadIdx.x;
    int chunk = (N + 1023) >> 10;
    int b = t * chunk, e = b + chunk; if (e > N) e = N;
    int s = 0;
    for (int i = b; i < e; ++i) s += cnt[i];
    sums[t] = s;
    __syncthreads();
    for (int o = 1; o < 1024; o <<= 1) {
        int v = (t >= o) ? sums[t - o] : 0;
        __syncthreads();
        sums[t] += v;
        __syncthreads();
    }
    int run = (t == 0) ? 0 : sums[t - 1];
    for (int i = b; i < e; ++i) {
        int c = cnt[i];
        indptr[i] = run;
        cnt[i] = run;      // becomes the scatter cursor
        run += c;
    }
    if (b < N && e == N) indptr[N] = run;
}

__global__ void scatter_edges(const int* __restrict__ src, const int* __restrict__ dst,
                              int* __restrict__ cursor, int* __restrict__ csr,
                              int E, int N) {
    int i = blockIdx.x * blockDim.x + threadIdx.x;
    if (i < E) {
        int p = atomicAdd(&cursor[dst[i]], 1);
        csr[p] = src[i];
    } else if (i < E + N) {
        int n = i - E;
        int p = atomicAdd(&cursor[n], 1);
        csr[p] = n;        // self-loop
    }
}

// ---------------- GEMM: out[N,128] = A[N,128] @ W[128,128] (fp32) ----------------
// grid: (ceil(N/128), 2). Block 256. Each block: 64 cols (blockIdx.y half) x 128 rows.
#define G_ROWS 128
__global__ __launch_bounds__(256) void gemm128(const float* __restrict__ A,
                                               const float* __restrict__ W,
                                               float* __restrict__ out, int N) {
    __shared__ __align__(16) float Wt[64 * 132];   // transposed half of W, stride 132
    __shared__ __align__(16) float xs[16 * 128];   // 16 staged rows
    const int tid = threadIdx.x;
    const int ch  = blockIdx.y;                    // column half: 0 or 1

    // stage W half, transposed: Wt[c*132 + k] = W[k*128 + ch*64 + c]
    for (int idx = tid; idx < 128 * 64; idx += 256) {
        int k = idx >> 6, c = idx & 63;
        Wt[c * 132 + k] = W[k * 128 + ch * 64 + c];
    }
    __syncthreads();

    const int col = tid & 63;       // 0..63 within half
    const int rg  = tid >> 6;       // 0..3 row group
    const float4* wp = (const float4*)&Wt[col * 132];

    for (int it = 0; it < G_ROWS / 16; ++it) {
        int r0 = blockIdx.x * G_ROWS + it * 16;
        // stage 16 rows of A (2048 floats, 2 float4 per thread, conflict-free)
        {
            int f0 = tid * 4;                 // flat float index
            int row = f0 >> 7, k = f0 & 127;
            int gr = r0 + row;
            float4 v = make_float4(0.f, 0.f, 0.f, 0.f);
            if (gr < N) v = *(const float4*)&A[(size_t)gr * HD + k];
            *(float4*)&xs[f0] = v;
            int f1 = f0 + 1024;
            row = f1 >> 7; k = f1 & 127;
            gr = r0 + row;
            v = make_float4(0.f, 0.f, 0.f, 0.f);
            if (gr < N) v = *(const float4*)&A[(size_t)gr * HD + k];
            *(float4*)&xs[f1] = v;
        }
        __syncthreads();

        float acc0 = 0.f, acc1 = 0.f, acc2 = 0.f, acc3 = 0.f;
        const float4* x0 = (const float4*)&xs[(rg * 4 + 0) * 128];
        const float4* x1 = (const float4*)&xs[(rg * 4 + 1) * 128];
        const float4* x2 = (const float4*)&xs[(rg * 4 + 2) * 128];
        const float4* x3 = (const float4*)&xs[(rg * 4 + 3) * 128];
        #pragma unroll 8
        for (int g = 0; g < 32; ++g) {
            float4 w4 = wp[g];
            float4 a;
            a = x0[g]; acc0 += a.x * w4.x + a.y * w4.y + a.z * w4.z + a.w * w4.w;
            a = x1[g]; acc1 += a.x * w4.x + a.y * w4.y + a.z * w4.z + a.w * w4.w;
            a = x2[g]; acc2 += a.x * w4.x + a.y * w4.y + a.z * w4.z + a.w * w4.w;
            a = x3[g]; acc3 += a.x * w4.x + a.y * w4.y + a.z * w4.z + a.w * w4.w;
        }
        int rr = r0 + rg * 4;
        int oc = ch * 64 + col;
        if (rr + 0 < N) out[(size_t)(rr + 0) * HD + oc] = acc0;
        if (rr + 1 < N) out[(size_t)(rr + 1) * HD + oc] = acc1;
        if (rr + 2 < N) out[(size_t)(rr + 2) * HD + oc] = acc2;
        if (rr + 3 < N) out[(size_t)(rr + 3) * HD + oc] = acc3;
        __syncthreads();
    }
}

// ---------------- per-node attention logits ----------------
// one wave per node: al_s[n][h] = sum_c h[n,h,c]*a_src[h,c]; same for a_dst
__global__ __launch_bounds__(256) void attn_logits(const float* __restrict__ h,
                                                   const float* __restrict__ a_s,
                                                   const float* __restrict__ a_d,
                                                   float* __restrict__ als,
                                                   float* __restrict__ ald, int N) {
    int gw   = (blockIdx.x * blockDim.x + threadIdx.x) >> 6;
    int lane = threadIdx.x & 63;
    if (gw >= N) return;
    int c = lane * 2;
    float2 hv = *(const float2*)&h[(size_t)gw * HD + c];
    float s = hv.x * a_s[c] + hv.y * a_s[c + 1];
    float d = hv.x * a_d[c] + hv.y * a_d[c + 1];
    // lanes 0..31 = head0, 32..63 = head1 (xor<=16 stays within half)
    for (int o = 16; o >= 1; o >>= 1) {
        s += __shfl_xor(s, o, 64);
        d += __shfl_xor(d, o, 64);
    }
    if (lane == 0)  { als[2 * gw]     = s; ald[2 * gw]     = d; }
    if (lane == 32) { als[2 * gw + 1] = s; ald[2 * gw + 1] = d; }
}

// ---------------- GAT aggregation: one wave per dst node ----------------
__global__ __launch_bounds__(256) void gat_aggregate(const float* __restrict__ h,
                                                     const float* __restrict__ als,
                                                     const float* __restrict__ ald,
                                                     const int* __restrict__ indptr,
                                                     const int* __restrict__ csr,
                                                     const float* __restrict__ bias,
                                                     float* __restrict__ out, int N) {
    int w    = (blockIdx.x * blockDim.x + threadIdx.x) >> 6;
    int lane = threadIdx.x & 63;
    if (w >= N) return;
    int start = indptr[w], end = indptr[w + 1];
    float ad0 = ald[2 * w], ad1 = ald[2 * w + 1];

    // pass 1: per-head max of leaky_relu(al_s[src]+al_d[dst])
    float m0 = -INFINITY, m1 = -INFINITY;
    for (int i = start + lane; i < end; i += 64) {
        int s = csr[i];
        float e0 = als[2 * s] + ad0;
        float e1 = als[2 * s + 1] + ad1;
        e0 = e0 > 0.f ? e0 : NEG_SLOPE * e0;
        e1 = e1 > 0.f ? e1 : NEG_SLOPE * e1;
        m0 = fmaxf(m0, e0); m1 = fmaxf(m1, e1);
    }
    for (int o = 32; o >= 1; o >>= 1) {
        m0 = fmaxf(m0, __shfl_xor(m0, o, 64));
        m1 = fmaxf(m1, __shfl_xor(m1, o, 64));
    }

    // pass 2: acc = sum exp(e-m)*h[src]; denom = sum exp(e-m)
    float accx = 0.f, accy = 0.f, d0 = 0.f, d1 = 0.f;
    const int cbase = lane * 2;   // lane<32 -> head0 channels, lane>=32 -> head1
    for (int base = start; base < end; base += 64) {
        int i = base + lane;
        float w0 = 0.f, w1 = 0.f; int s = 0;
        if (i < end) {
            s = csr[i];
            float e0 = als[2 * s] + ad0;
            float e1 = als[2 * s + 1] + ad1;
            e0 = e0 > 0.f ? e0 : NEG_SLOPE * e0;
            e1 = e1 > 0.f ? e1 : NEG_SLOPE * e1;
            w0 = __expf(e0 - m0);
            w1 = __expf(e1 - m1);
        }
        d0 += w0; d1 += w1;
        int nl = end - base; if (nl > 64) nl = 64;
        for (int j = 0; j < nl; ++j) {
            int   sj  = __shfl(s,  j, 64);
            float wj0 = __shfl(w0, j, 64);
            float wj1 = __shfl(w1, j, 64);
            float wj = (lane < 32) ? wj0 : wj1;
            float2 hv = *(const float2*)&h[(size_t)sj * HD + cbase];
            accx += wj * hv.x;
            accy += wj * hv.y;
        }
    }
    for (int o = 32; o >= 1; o >>= 1) {
        d0 += __shfl_xor(d0, o, 64);
        d1 += __shfl_xor(d1, o, 64);
    }
    float D = ((lane < 32) ? d0 : d1) + EPSV;
    float ox = accx / D + bias[cbase];
    float oy = accy / D + bias[cbase + 1];
    ox = ox > 0.f ? ox : 0.f;   // ReLU (applied after both layers in reference)
    oy = oy > 0.f ? oy : 0.f;
    *(float2*)&out[(size_t)w * HD + cbase] = make_float2(ox, oy);
}

// ---------------- graph boundaries (batch is sorted) ----------------
__global__ void graph_bounds(const int* __restrict__ batch, int* __restrict__ gstart,
                             int N, int G) {
    int g = blockIdx.x * blockDim.x + threadIdx.x;
    if (g > G) return;
    int lo = 0, hi = N;
    while (lo < hi) {
        int mid = (lo + hi) >> 1;
        if (batch[mid] < g) lo = mid + 1; else hi = mid;
    }
    gstart[g] = lo;
}

// ---------------- mean pool + linear head ----------------
__global__ __launch_bounds__(256) void pool_head(const float* __restrict__ x,
                                                 const int* __restrict__ gstart,
                                                 const float* __restrict__ Wh,
                                                 const float* __restrict__ bh,
                                                 float* __restrict__ out, int G) {
    __shared__ float red[256];
    __shared__ float partial[4];
    int g = blockIdx.x;
    int t = threadIdx.x;
    int s = gstart[g], e = gstart[g + 1];
    int col = t & 127, half = t >> 7;
    float sum = 0.f;
    for (int n = s + half; n < e; n += 2) sum += x[(size_t)n * HD + col];
    red[t] = sum;
    __syncthreads();
    float tot = 0.f;
    if (t < 128) {
        float cnt = (float)(e - s); if (cnt < 1.f) cnt = 1.f;
        tot = (red[t] + red[t + 128]) / cnt * Wh[col];
    }
    for (int o = 32; o >= 1; o >>= 1) tot += __shfl_xor(tot, o, 64);
    if ((t & 63) == 0) partial[t >> 6] = tot;
    __syncthreads();
    if (t == 0) out[g] = partial[0] + partial[1] + partial[2] + partial[3] + bh[0];
}

// ---------------- launch ----------------
extern "C" void kernel_launch(void* const* d_in, const int* in_sizes, int n_in,
                              void* d_out, int out_size, void* d_ws, size_t ws_size,
                              hipStream_t stream) {
    const float* x     = (const float*)d_in[0];
    const int*   ei    = (const int*)d_in[1];
    const int*   batch = (const int*)d_in[2];
    const float* W1  = (const float*)d_in[3];
    const float* as1 = (const float*)d_in[4];
    const float* ad1 = (const float*)d_in[5];
    const float* b1  = (const float*)d_in[6];
    const float* W2  = (const float*)d_in[7];
    const float* as2 = (const float*)d_in[8];
    const float* ad2 = (const float*)d_in[9];
    const float* b2  = (const float*)d_in[10];
    const float* Wh  = (const float*)d_in[11];
    const float* bh  = (const float*)d_in[12];
    float* out = (float*)d_out;

    const int N = in_sizes[0] / HD;
    const int E = in_sizes[1] / 2;
    const int G = out_size;
    const int* srcp = ei;
    const int* dstp = ei + E;

    char* ws = (char*)d_ws;
    size_t off = 0;
    auto alloc = [&](size_t bytes) -> void* {
        void* p = ws + off;
        off += (bytes + 255) & ~(size_t)255;
        return p;
    };
    float* h      = (float*)alloc((size_t)N * HD * 4);
    float* ob     = (float*)alloc((size_t)N * HD * 4);
    float* als    = (float*)alloc((size_t)N * 2 * 4);
    float* ald    = (float*)alloc((size_t)N * 2 * 4);
    int*   indptr = (int*)  alloc((size_t)(N + 1) * 4);
    int*   cursor = (int*)  alloc((size_t)N * 4);
    int*   csr    = (int*)  alloc((size_t)(E + N) * 4);
    int*   gstart = (int*)  alloc((size_t)(G + 1) * 4);

    // CSR build (shared by both layers)
    init_counts<<<(N + 255) / 256, 256, 0, stream>>>(cursor, N);
    count_edges<<<(E + 255) / 256, 256, 0, stream>>>(dstp, cursor, E);
    scan_counts<<<1, 1024, 0, stream>>>(cursor, indptr, N);
    scatter_edges<<<(E + N + 255) / 256, 256, 0, stream>>>(srcp, dstp, cursor, csr, E, N);
    graph_bounds<<<1, 64, 0, stream>>>(batch, gstart, N, G);

    dim3 ggrid((N + G_ROWS - 1) / G_ROWS, 2);
    int  wgrid = (N * 64 + 255) / 256;

    // layer 1
    gemm128<<<ggrid, 256, 0, stream>>>(x, W1, h, N);
    attn_logits<<<wgrid, 256, 0, stream>>>(h, as1, ad1, als, ald, N);
    gat_aggregate<<<wgrid, 256, 0, stream>>>(h, als, ald, indptr, csr, b1, ob, N);
    // layer 2
    gemm128<<<ggrid, 256, 0, stream>>>(ob, W2, h, N);
    attn_logits<<<wgrid, 256, 0, stream>>>(h, as2, ad2, als, ald, N);
    gat_aggregate<<<wgrid, 256, 0, stream>>>(h, als, ald, indptr, csr, b2, ob, N);
    // pool + head
    pool_head<<<G, 256, 0, stream>>>(ob, gstart, Wh, bh, out, G);
}

// Round 2
// 619.718 us; speedup vs baseline: 1.2017x; 1.2017x over previous
//
#include <hip/hip_runtime.h>
#include <math.h>

#define HD 128          // hidden dim (= H*C = D_IN)
#define NEG_SLOPE 0.2f
#define EPSV 1e-16f

// ---------------- CSR build ----------------
__global__ void init_counts(int* __restrict__ cnt, int N) {
    int i = blockIdx.x * blockDim.x + threadIdx.x;
    if (i < N) cnt[i] = 1;   // self-loop pre-count
}

__global__ void count_edges(const int* __restrict__ dst, int* __restrict__ cnt, int E) {
    int i = blockIdx.x * blockDim.x + threadIdx.x;
    if (i < E) atomicAdd(&cnt[dst[i]], 1);
}

__global__ __launch_bounds__(1024) void scan_counts(int* __restrict__ cnt,
                                                    int* __restrict__ indptr, int N) {
    __shared__ int sums[1024];
    int t = threadIdx.x;
    int chunk = (N + 1023) >> 10;
    int b = t * chunk, e = b + chunk; if (e > N) e = N;
    int s = 0;
    for (int i = b; i < e; ++i) s += cnt[i];
    sums[t] = s;
    __syncthreads();
    for (int o = 1; o < 1024; o <<= 1) {
        int v = (t >= o) ? sums[t - o] : 0;
        __syncthreads();
        sums[t] += v;
        __syncthreads();
    }
    int run = (t == 0) ? 0 : sums[t - 1];
    for (int i = b; i < e; ++i) {
        int c = cnt[i];
        indptr[i] = run;
        cnt[i] = run;      // becomes the scatter cursor
        run += c;
    }
    if (b < N && e == N) indptr[N] = run;
}

__global__ void scatter_edges(const int* __restrict__ src, const int* __restrict__ dst,
                              int* __restrict__ cursor, int* __restrict__ csr,
                              int E, int N) {
    int i = blockIdx.x * blockDim.x + threadIdx.x;
    if (i < E) {
        int p = atomicAdd(&cursor[dst[i]], 1);
        csr[p] = src[i];
    } else if (i < E + N) {
        int n = i - E;
        int p = atomicAdd(&cursor[n], 1);
        csr[p] = n;        // self-loop
    }
}

// ---------------- GEMM: out[N,128] = A[N,128] @ W[128,128] (fp32) ----------------
// grid: (ceil(N/128), 2). Block 256. Each block: 64 cols (blockIdx.y half) x 128 rows.
#define G_ROWS 128
__global__ __launch_bounds__(256) void gemm128(const float* __restrict__ A,
                                               const float* __restrict__ W,
                                               float* __restrict__ out, int N) {
    __shared__ __align__(16) float Wt[64 * 132];   // transposed half of W, stride 132
    __shared__ __align__(16) float xs[16 * 128];   // 16 staged rows
    const int tid = threadIdx.x;
    const int ch  = blockIdx.y;                    // column half: 0 or 1

    // stage W half, transposed: Wt[c*132 + k] = W[k*128 + ch*64 + c]
    for (int idx = tid; idx < 128 * 64; idx += 256) {
        int k = idx >> 6, c = idx & 63;
        Wt[c * 132 + k] = W[k * 128 + ch * 64 + c];
    }
    __syncthreads();

    const int col = tid & 63;       // 0..63 within half
    const int rg  = tid >> 6;       // 0..3 row group
    const float4* wp = (const float4*)&Wt[col * 132];

    for (int it = 0; it < G_ROWS / 16; ++it) {
        int r0 = blockIdx.x * G_ROWS + it * 16;
        // stage 16 rows of A (2048 floats, 2 float4 per thread, conflict-free)
        {
            int f0 = tid * 4;                 // flat float index
            int row = f0 >> 7, k = f0 & 127;
            int gr = r0 + row;
            float4 v = make_float4(0.f, 0.f, 0.f, 0.f);
            if (gr < N) v = *(const float4*)&A[(size_t)gr * HD + k];
            *(float4*)&xs[f0] = v;
            int f1 = f0 + 1024;
            row = f1 >> 7; k = f1 & 127;
            gr = r0 + row;
            v = make_float4(0.f, 0.f, 0.f, 0.f);
            if (gr < N) v = *(const float4*)&A[(size_t)gr * HD + k];
            *(float4*)&xs[f1] = v;
        }
        __syncthreads();

        float acc0 = 0.f, acc1 = 0.f, acc2 = 0.f, acc3 = 0.f;
        const float4* x0 = (const float4*)&xs[(rg * 4 + 0) * 128];
        const float4* x1 = (const float4*)&xs[(rg * 4 + 1) * 128];
        const float4* x2 = (const float4*)&xs[(rg * 4 + 2) * 128];
        const float4* x3 = (const float4*)&xs[(rg * 4 + 3) * 128];
        #pragma unroll 8
        for (int g = 0; g < 32; ++g) {
            float4 w4 = wp[g];
            float4 a;
            a = x0[g]; acc0 += a.x * w4.x + a.y * w4.y + a.z * w4.z + a.w * w4.w;
            a = x1[g]; acc1 += a.x * w4.x + a.y * w4.y + a.z * w4.z + a.w * w4.w;
            a = x2[g]; acc2 += a.x * w4.x + a.y * w4.y + a.z * w4.z + a.w * w4.w;
            a = x3[g]; acc3 += a.x * w4.x + a.y * w4.y + a.z * w4.z + a.w * w4.w;
        }
        int rr = r0 + rg * 4;
        int oc = ch * 64 + col;
        if (rr + 0 < N) out[(size_t)(rr + 0) * HD + oc] = acc0;
        if (rr + 1 < N) out[(size_t)(rr + 1) * HD + oc] = acc1;
        if (rr + 2 < N) out[(size_t)(rr + 2) * HD + oc] = acc2;
        if (rr + 3 < N) out[(size_t)(rr + 3) * HD + oc] = acc3;
        __syncthreads();
    }
}

// ---------------- per-node attention logits ----------------
__global__ __launch_bounds__(256) void attn_logits(const float* __restrict__ h,
                                                   const float* __restrict__ a_s,
                                                   const float* __restrict__ a_d,
                                                   float* __restrict__ als,
                                                   float* __restrict__ ald, int N) {
    int gw   = (blockIdx.x * blockDim.x + threadIdx.x) >> 6;
    int lane = threadIdx.x & 63;
    if (gw >= N) return;
    int c = lane * 2;
    float2 hv = *(const float2*)&h[(size_t)gw * HD + c];
    float s = hv.x * a_s[c] + hv.y * a_s[c + 1];
    float d = hv.x * a_d[c] + hv.y * a_d[c + 1];
    // lanes 0..31 = head0, 32..63 = head1 (xor<=16 stays within half)
    for (int o = 16; o >= 1; o >>= 1) {
        s += __shfl_xor(s, o, 64);
        d += __shfl_xor(d, o, 64);
    }
    if (lane == 0)  { als[2 * gw]     = s; ald[2 * gw]     = d; }
    if (lane == 32) { als[2 * gw + 1] = s; ald[2 * gw + 1] = d; }
}

// ---------------- GAT aggregation: one wave per dst node ----------------
// If svec != nullptr: instead of writing out[], compute s[w] = relu(o)·Wh
// (the mean-pool head is linear, so per-node dot products suffice).
__global__ __launch_bounds__(256) void gat_aggregate(const float* __restrict__ h,
                                                     const float* __restrict__ als,
                                                     const float* __restrict__ ald,
                                                     const int* __restrict__ indptr,
                                                     const int* __restrict__ csr,
                                                     const float* __restrict__ bias,
                                                     float* __restrict__ out,
                                                     const float* __restrict__ Wh,
                                                     float* __restrict__ svec, int N) {
    int w    = (blockIdx.x * blockDim.x + threadIdx.x) >> 6;
    int lane = threadIdx.x & 63;
    if (w >= N) return;
    int start = indptr[w], end = indptr[w + 1];
    float ad0 = ald[2 * w], ad1 = ald[2 * w + 1];

    // pass 1: per-head max of leaky_relu(al_s[src]+al_d[dst])
    float m0 = -INFINITY, m1 = -INFINITY;
    for (int i = start + lane; i < end; i += 64) {
        int s = csr[i];
        float e0 = als[2 * s] + ad0;
        float e1 = als[2 * s + 1] + ad1;
        e0 = e0 > 0.f ? e0 : NEG_SLOPE * e0;
        e1 = e1 > 0.f ? e1 : NEG_SLOPE * e1;
        m0 = fmaxf(m0, e0); m1 = fmaxf(m1, e1);
    }
    for (int o = 32; o >= 1; o >>= 1) {
        m0 = fmaxf(m0, __shfl_xor(m0, o, 64));
        m1 = fmaxf(m1, __shfl_xor(m1, o, 64));
    }

    // pass 2: acc = sum exp(e-m)*h[src]; denom = sum exp(e-m)
    float accx = 0.f, accy = 0.f, d0 = 0.f, d1 = 0.f;
    const int cbase = lane * 2;   // lane<32 -> head0 channels, lane>=32 -> head1
    for (int base = start; base < end; base += 64) {
        int i = base + lane;
        float w0 = 0.f, w1 = 0.f; int s = 0;
        if (i < end) {
            s = csr[i];
            float e0 = als[2 * s] + ad0;
            float e1 = als[2 * s + 1] + ad1;
            e0 = e0 > 0.f ? e0 : NEG_SLOPE * e0;
            e1 = e1 > 0.f ? e1 : NEG_SLOPE * e1;
            w0 = __expf(e0 - m0);
            w1 = __expf(e1 - m1);
        }
        d0 += w0; d1 += w1;
        int nl = end - base; if (nl > 64) nl = 64;
        for (int j = 0; j < nl; ++j) {
            int   sj  = __shfl(s,  j, 64);
            float wj0 = __shfl(w0, j, 64);
            float wj1 = __shfl(w1, j, 64);
            float wj = (lane < 32) ? wj0 : wj1;
            float2 hv = *(const float2*)&h[(size_t)sj * HD + cbase];
            accx += wj * hv.x;
            accy += wj * hv.y;
        }
    }
    for (int o = 32; o >= 1; o >>= 1) {
        d0 += __shfl_xor(d0, o, 64);
        d1 += __shfl_xor(d1, o, 64);
    }
    float D = ((lane < 32) ? d0 : d1) + EPSV;
    float ox = accx / D + bias[cbase];
    float oy = accy / D + bias[cbase + 1];
    ox = ox > 0.f ? ox : 0.f;   // ReLU
    oy = oy > 0.f ? oy : 0.f;

    if (svec) {
        float2 wv = *(const float2*)&Wh[cbase];
        float part = ox * wv.x + oy * wv.y;
        for (int o = 32; o >= 1; o >>= 1) part += __shfl_xor(part, o, 64);
        if (lane == 0) svec[w] = part;
    } else {
        *(float2*)&out[(size_t)w * HD + cbase] = make_float2(ox, oy);
    }
}

// ---------------- graph boundaries (batch is sorted) ----------------
__global__ void graph_bounds(const int* __restrict__ batch, int* __restrict__ gstart,
                             int N, int G) {
    int g = blockIdx.x * blockDim.x + threadIdx.x;
    if (g > G) return;
    int lo = 0, hi = N;
    while (lo < hi) {
        int mid = (lo + hi) >> 1;
        if (batch[mid] < g) lo = mid + 1; else hi = mid;
    }
    gstart[g] = lo;
}

// ---------------- per-graph reduce of per-node head dots ----------------
__global__ __launch_bounds__(256) void pool_reduce(const float* __restrict__ s,
                                                   const int* __restrict__ gstart,
                                                   const float* __restrict__ bh,
                                                   float* __restrict__ out, int G) {
    __shared__ float partial[4];
    int g = blockIdx.x, t = threadIdx.x;
    int a = gstart[g], b = gstart[g + 1];
    float sum = 0.f;
    for (int i = a + t; i < b; i += 256) sum += s[i];
    for (int o = 32; o >= 1; o >>= 1) sum += __shfl_xor(sum, o, 64);
    if ((t & 63) == 0) partial[t >> 6] = sum;
    __syncthreads();
    if (t == 0) {
        float cnt = (float)(b - a); if (cnt < 1.f) cnt = 1.f;
        out[g] = (partial[0] + partial[1] + partial[2] + partial[3]) / cnt + bh[0];
    }
}

// ---------------- launch ----------------
extern "C" void kernel_launch(void* const* d_in, const int* in_sizes, int n_in,
                              void* d_out, int out_size, void* d_ws, size_t ws_size,
                              hipStream_t stream) {
    const float* x     = (const float*)d_in[0];
    const int*   ei    = (const int*)d_in[1];
    const int*   batch = (const int*)d_in[2];
    const float* W1  = (const float*)d_in[3];
    const float* as1 = (const float*)d_in[4];
    const float* ad1 = (const float*)d_in[5];
    const float* b1  = (const float*)d_in[6];
    const float* W2  = (const float*)d_in[7];
    const float* as2 = (const float*)d_in[8];
    const float* ad2 = (const float*)d_in[9];
    const float* b2  = (const float*)d_in[10];
    const float* Wh  = (const float*)d_in[11];
    const float* bh  = (const float*)d_in[12];
    float* out = (float*)d_out;

    const int N = in_sizes[0] / HD;
    const int E = in_sizes[1] / 2;
    const int G = out_size;
    const int* srcp = ei;
    const int* dstp = ei + E;

    char* ws = (char*)d_ws;
    size_t off = 0;
    auto alloc = [&](size_t bytes) -> void* {
        void* p = ws + off;
        off += (bytes + 255) & ~(size_t)255;
        return p;
    };
    float* h      = (float*)alloc((size_t)N * HD * 4);
    float* ob     = (float*)alloc((size_t)N * HD * 4);
    float* als    = (float*)alloc((size_t)N * 2 * 4);
    float* ald    = (float*)alloc((size_t)N * 2 * 4);
    float* svec   = (float*)alloc((size_t)N * 4);
    int*   indptr = (int*)  alloc((size_t)(N + 1) * 4);
    int*   cursor = (int*)  alloc((size_t)N * 4);
    int*   csr    = (int*)  alloc((size_t)(E + N) * 4);
    int*   gstart = (int*)  alloc((size_t)(G + 1) * 4);

    // CSR build (shared by both layers)
    init_counts<<<(N + 255) / 256, 256, 0, stream>>>(cursor, N);
    count_edges<<<(E + 255) / 256, 256, 0, stream>>>(dstp, cursor, E);
    scan_counts<<<1, 1024, 0, stream>>>(cursor, indptr, N);
    scatter_edges<<<(E + N + 255) / 256, 256, 0, stream>>>(srcp, dstp, cursor, csr, E, N);
    graph_bounds<<<1, 64, 0, stream>>>(batch, gstart, N, G);

    dim3 ggrid((N + G_ROWS - 1) / G_ROWS, 2);
    int  wgrid = (N * 64 + 255) / 256;

    // layer 1
    gemm128<<<ggrid, 256, 0, stream>>>(x, W1, h, N);
    attn_logits<<<wgrid, 256, 0, stream>>>(h, as1, ad1, als, ald, N);
    gat_aggregate<<<wgrid, 256, 0, stream>>>(h, als, ald, indptr, csr, b1, ob,
                                             nullptr, nullptr, N);
    // layer 2
    gemm128<<<ggrid, 256, 0, stream>>>(ob, W2, h, N);
    attn_logits<<<wgrid, 256, 0, stream>>>(h, as2, ad2, als, ald, N);
    gat_aggregate<<<wgrid, 256, 0, stream>>>(h, als, ald, indptr, csr, b2, nullptr,
                                             Wh, svec, N);
    // pool + head (tiny: 50 blocks x ~1000 scalars)
    pool_reduce<<<G, 256, 0, stream>>>(svec, gstart, bh, out, G);
}

// Round 3
// 524.193 us; speedup vs baseline: 1.4207x; 1.1822x over previous
//
#include <hip/hip_runtime.h>
#include <math.h>

#define HD 128          // hidden dim (= H*C = D_IN)
#define NEG_SLOPE 0.2f
#define EPSV 1e-16f

// ---------------- CSR build ----------------
__global__ void init_counts(int* __restrict__ cnt, int N) {
    int i = blockIdx.x * blockDim.x + threadIdx.x;
    if (i < N) cnt[i] = 1;   // self-loop pre-count
}

__global__ void count_edges(const int* __restrict__ dst, int* __restrict__ cnt, int E) {
    int i = blockIdx.x * blockDim.x + threadIdx.x;
    if (i < E) atomicAdd(&cnt[dst[i]], 1);
}

// hierarchical scan, stage 1: per-256-chunk sums
__global__ __launch_bounds__(256) void block_sums(const int* __restrict__ cnt,
                                                  int* __restrict__ bsum, int N) {
    __shared__ int s[4];
    int t = threadIdx.x;
    int i = blockIdx.x * 256 + t;
    int v = (i < N) ? cnt[i] : 0;
    for (int o = 32; o >= 1; o >>= 1) v += __shfl_xor(v, o, 64);
    if ((t & 63) == 0) s[t >> 6] = v;
    __syncthreads();
    if (t == 0) bsum[blockIdx.x] = s[0] + s[1] + s[2] + s[3];
}

// stage 2: exclusive scan of block sums (single block, tiles of 256 w/ carry)
__global__ __launch_bounds__(256) void scan_bsums(int* __restrict__ bsum, int NB) {
    __shared__ int s[256];
    __shared__ int carry;
    int t = threadIdx.x;
    if (t == 0) carry = 0;
    __syncthreads();
    for (int base = 0; base < NB; base += 256) {
        int i = base + t;
        int v = (i < NB) ? bsum[i] : 0;
        s[t] = v;
        __syncthreads();
        for (int o = 1; o < 256; o <<= 1) {
            int u = (t >= o) ? s[t - o] : 0;
            __syncthreads();
            s[t] += u;
            __syncthreads();
        }
        int excl = ((t == 0) ? 0 : s[t - 1]) + carry;
        if (i < NB) bsum[i] = excl;
        __syncthreads();
        if (t == 0) carry += s[255];
        __syncthreads();
    }
}

// stage 3: in-block exclusive scan + block offset -> indptr & cursor
__global__ __launch_bounds__(256) void scatter_scan(const int* __restrict__ cnt,
                                                    const int* __restrict__ bsum,
                                                    int* __restrict__ indptr,
                                                    int* __restrict__ cursor, int N) {
    __shared__ int s[256];
    int t = threadIdx.x;
    int i = blockIdx.x * 256 + t;
    int v = (i < N) ? cnt[i] : 0;
    s[t] = v;
    __syncthreads();
    for (int o = 1; o < 256; o <<= 1) {
        int u = (t >= o) ? s[t - o] : 0;
        __syncthreads();
        s[t] += u;
        __syncthreads();
    }
    int excl = ((t == 0) ? 0 : s[t - 1]) + bsum[blockIdx.x];
    if (i < N) { indptr[i] = excl; cursor[i] = excl; }
    if (i == N - 1) indptr[N] = excl + v;
}

__global__ void scatter_edges(const int* __restrict__ src, const int* __restrict__ dst,
                              int* __restrict__ cursor, int* __restrict__ csr,
                              int E, int N) {
    int i = blockIdx.x * blockDim.x + threadIdx.x;
    if (i < E) {
        int p = atomicAdd(&cursor[dst[i]], 1);
        csr[p] = src[i];
    } else if (i < E + N) {
        int n = i - E;
        int p = atomicAdd(&cursor[n], 1);
        csr[p] = n;        // self-loop
    }
}

// ---------------- GEMM: out[N,128] = A[N,128] @ W[128,128] (fp32) ----------------
// grid: (ceil(N/128), 2). Block 256. Each block: 64 cols (blockIdx.y half) x 128 rows.
#define G_ROWS 128
__global__ __launch_bounds__(256) void gemm128(const float* __restrict__ A,
                                               const float* __restrict__ W,
                                               float* __restrict__ out, int N) {
    __shared__ __align__(16) float Wt[64 * 132];   // transposed half of W, stride 132
    __shared__ __align__(16) float xs[16 * 128];   // 16 staged rows
    const int tid = threadIdx.x;
    const int ch  = blockIdx.y;                    // column half: 0 or 1

    // stage W half, transposed: Wt[c*132 + k] = W[k*128 + ch*64 + c]
    for (int idx = tid; idx < 128 * 64; idx += 256) {
        int k = idx >> 6, c = idx & 63;
        Wt[c * 132 + k] = W[k * 128 + ch * 64 + c];
    }
    __syncthreads();

    const int col = tid & 63;       // 0..63 within half
    const int rg  = tid >> 6;       // 0..3 row group
    const float4* wp = (const float4*)&Wt[col * 132];

    for (int it = 0; it < G_ROWS / 16; ++it) {
        int r0 = blockIdx.x * G_ROWS + it * 16;
        // stage 16 rows of A (2048 floats, 2 float4 per thread, conflict-free)
        {
            int f0 = tid * 4;                 // flat float index
            int row = f0 >> 7, k = f0 & 127;
            int gr = r0 + row;
            float4 v = make_float4(0.f, 0.f, 0.f, 0.f);
            if (gr < N) v = *(const float4*)&A[(size_t)gr * HD + k];
            *(float4*)&xs[f0] = v;
            int f1 = f0 + 1024;
            row = f1 >> 7; k = f1 & 127;
            gr = r0 + row;
            v = make_float4(0.f, 0.f, 0.f, 0.f);
            if (gr < N) v = *(const float4*)&A[(size_t)gr * HD + k];
            *(float4*)&xs[f1] = v;
        }
        __syncthreads();

        float acc0 = 0.f, acc1 = 0.f, acc2 = 0.f, acc3 = 0.f;
        const float4* x0 = (const float4*)&xs[(rg * 4 + 0) * 128];
        const float4* x1 = (const float4*)&xs[(rg * 4 + 1) * 128];
        const float4* x2 = (const float4*)&xs[(rg * 4 + 2) * 128];
        const float4* x3 = (const float4*)&xs[(rg * 4 + 3) * 128];
        #pragma unroll 8
        for (int g = 0; g < 32; ++g) {
            float4 w4 = wp[g];
            float4 a;
            a = x0[g]; acc0 += a.x * w4.x + a.y * w4.y + a.z * w4.z + a.w * w4.w;
            a = x1[g]; acc1 += a.x * w4.x + a.y * w4.y + a.z * w4.z + a.w * w4.w;
            a = x2[g]; acc2 += a.x * w4.x + a.y * w4.y + a.z * w4.z + a.w * w4.w;
            a = x3[g]; acc3 += a.x * w4.x + a.y * w4.y + a.z * w4.z + a.w * w4.w;
        }
        int rr = r0 + rg * 4;
        int oc = ch * 64 + col;
        if (rr + 0 < N) out[(size_t)(rr + 0) * HD + oc] = acc0;
        if (rr + 1 < N) out[(size_t)(rr + 1) * HD + oc] = acc1;
        if (rr + 2 < N) out[(size_t)(rr + 2) * HD + oc] = acc2;
        if (rr + 3 < N) out[(size_t)(rr + 3) * HD + oc] = acc3;
        __syncthreads();
    }
}

// ---------------- per-node attention logits ----------------
__global__ __launch_bounds__(256) void attn_logits(const float* __restrict__ h,
                                                   const float* __restrict__ a_s,
                                                   const float* __restrict__ a_d,
                                                   float* __restrict__ als,
                                                   float* __restrict__ ald, int N) {
    int gw   = (blockIdx.x * blockDim.x + threadIdx.x) >> 6;
    int lane = threadIdx.x & 63;
    if (gw >= N) return;
    int c = lane * 2;
    float2 hv = *(const float2*)&h[(size_t)gw * HD + c];
    float s = hv.x * a_s[c] + hv.y * a_s[c + 1];
    float d = hv.x * a_d[c] + hv.y * a_d[c + 1];
    // lanes 0..31 = head0, 32..63 = head1 (xor<=16 stays within half)
    for (int o = 16; o >= 1; o >>= 1) {
        s += __shfl_xor(s, o, 64);
        d += __shfl_xor(d, o, 64);
    }
    if (lane == 0)  { als[2 * gw]     = s; ald[2 * gw]     = d; }
    if (lane == 32) { als[2 * gw + 1] = s; ald[2 * gw + 1] = d; }
}

// ---------------- GAT aggregation: one wave per dst node ----------------
// If svec != nullptr: instead of writing out[], compute s[w] = relu(o)·Wh
// (the mean-pool head is linear, so per-node dot products suffice).
__global__ __launch_bounds__(256) void gat_aggregate(const float* __restrict__ h,
                                                     const float* __restrict__ als,
                                                     const float* __restrict__ ald,
                                                     const int* __restrict__ indptr,
                                                     const int* __restrict__ csr,
                                                     const float* __restrict__ bias,
                                                     float* __restrict__ out,
                                                     const float* __restrict__ Wh,
                                                     float* __restrict__ svec, int N) {
    int w    = (blockIdx.x * blockDim.x + threadIdx.x) >> 6;
    int lane = threadIdx.x & 63;
    if (w >= N) return;
    int start = indptr[w], end = indptr[w + 1];
    float ad0 = ald[2 * w], ad1 = ald[2 * w + 1];

    // pass 1: per-head max of leaky_relu(al_s[src]+al_d[dst])
    float m0 = -INFINITY, m1 = -INFINITY;
    for (int i = start + lane; i < end; i += 64) {
        int s = csr[i];
        float e0 = als[2 * s] + ad0;
        float e1 = als[2 * s + 1] + ad1;
        e0 = e0 > 0.f ? e0 : NEG_SLOPE * e0;
        e1 = e1 > 0.f ? e1 : NEG_SLOPE * e1;
        m0 = fmaxf(m0, e0); m1 = fmaxf(m1, e1);
    }
    for (int o = 32; o >= 1; o >>= 1) {
        m0 = fmaxf(m0, __shfl_xor(m0, o, 64));
        m1 = fmaxf(m1, __shfl_xor(m1, o, 64));
    }

    // pass 2: acc = sum exp(e-m)*h[src]; denom = sum exp(e-m)
    float accx = 0.f, accy = 0.f, d0 = 0.f, d1 = 0.f;
    const int cbase = lane * 2;   // lane<32 -> head0 channels, lane>=32 -> head1
    for (int base = start; base < end; base += 64) {
        int i = base + lane;
        float w0 = 0.f, w1 = 0.f; int s = 0;
        if (i < end) {
            s = csr[i];
            float e0 = als[2 * s] + ad0;
            float e1 = als[2 * s + 1] + ad1;
            e0 = e0 > 0.f ? e0 : NEG_SLOPE * e0;
            e1 = e1 > 0.f ? e1 : NEG_SLOPE * e1;
            w0 = __expf(e0 - m0);
            w1 = __expf(e1 - m1);
        }
        d0 += w0; d1 += w1;
        int nl = end - base; if (nl > 64) nl = 64;
        for (int j = 0; j < nl; ++j) {
            int   sj  = __shfl(s,  j, 64);
            float wj0 = __shfl(w0, j, 64);
            float wj1 = __shfl(w1, j, 64);
            float wj = (lane < 32) ? wj0 : wj1;
            float2 hv = *(const float2*)&h[(size_t)sj * HD + cbase];
            accx += wj * hv.x;
            accy += wj * hv.y;
        }
    }
    for (int o = 32; o >= 1; o >>= 1) {
        d0 += __shfl_xor(d0, o, 64);
        d1 += __shfl_xor(d1, o, 64);
    }
    float D = ((lane < 32) ? d0 : d1) + EPSV;
    float ox = accx / D + bias[cbase];
    float oy = accy / D + bias[cbase + 1];
    ox = ox > 0.f ? ox : 0.f;   // ReLU
    oy = oy > 0.f ? oy : 0.f;

    if (svec) {
        float2 wv = *(const float2*)&Wh[cbase];
        float part = ox * wv.x + oy * wv.y;
        for (int o = 32; o >= 1; o >>= 1) part += __shfl_xor(part, o, 64);
        if (lane == 0) svec[w] = part;
    } else {
        *(float2*)&out[(size_t)w * HD + cbase] = make_float2(ox, oy);
    }
}

// ---------------- graph boundaries (batch is sorted) ----------------
__global__ void graph_bounds(const int* __restrict__ batch, int* __restrict__ gstart,
                             int N, int G) {
    int g = blockIdx.x * blockDim.x + threadIdx.x;
    if (g > G) return;
    int lo = 0, hi = N;
    while (lo < hi) {
        int mid = (lo + hi) >> 1;
        if (batch[mid] < g) lo = mid + 1; else hi = mid;
    }
    gstart[g] = lo;
}

// ---------------- per-graph reduce of per-node head dots ----------------
__global__ __launch_bounds__(256) void pool_reduce(const float* __restrict__ s,
                                                   const int* __restrict__ gstart,
                                                   const float* __restrict__ bh,
                                                   float* __restrict__ out, int G) {
    __shared__ float partial[4];
    int g = blockIdx.x, t = threadIdx.x;
    int a = gstart[g], b = gstart[g + 1];
    float sum = 0.f;
    for (int i = a + t; i < b; i += 256) sum += s[i];
    for (int o = 32; o >= 1; o >>= 1) sum += __shfl_xor(sum, o, 64);
    if ((t & 63) == 0) partial[t >> 6] = sum;
    __syncthreads();
    if (t == 0) {
        float cnt = (float)(b - a); if (cnt < 1.f) cnt = 1.f;
        out[g] = (partial[0] + partial[1] + partial[2] + partial[3]) / cnt + bh[0];
    }
}

// ---------------- launch ----------------
extern "C" void kernel_launch(void* const* d_in, const int* in_sizes, int n_in,
                              void* d_out, int out_size, void* d_ws, size_t ws_size,
                              hipStream_t stream) {
    const float* x     = (const float*)d_in[0];
    const int*   ei    = (const int*)d_in[1];
    const int*   batch = (const int*)d_in[2];
    const float* W1  = (const float*)d_in[3];
    const float* as1 = (const float*)d_in[4];
    const float* ad1 = (const float*)d_in[5];
    const float* b1  = (const float*)d_in[6];
    const float* W2  = (const float*)d_in[7];
    const float* as2 = (const float*)d_in[8];
    const float* ad2 = (const float*)d_in[9];
    const float* b2  = (const float*)d_in[10];
    const float* Wh  = (const float*)d_in[11];
    const float* bh  = (const float*)d_in[12];
    float* out = (float*)d_out;

    const int N = in_sizes[0] / HD;
    const int E = in_sizes[1] / 2;
    const int G = out_size;
    const int* srcp = ei;
    const int* dstp = ei + E;
    const int NB = (N + 255) / 256;

    char* ws = (char*)d_ws;
    size_t off = 0;
    auto alloc = [&](size_t bytes) -> void* {
        void* p = ws + off;
        off += (bytes + 255) & ~(size_t)255;
        return p;
    };
    float* h      = (float*)alloc((size_t)N * HD * 4);
    float* ob     = (float*)alloc((size_t)N * HD * 4);
    float* als    = (float*)alloc((size_t)N * 2 * 4);
    float* ald    = (float*)alloc((size_t)N * 2 * 4);
    float* svec   = (float*)alloc((size_t)N * 4);
    int*   indptr = (int*)  alloc((size_t)(N + 1) * 4);
    int*   cursor = (int*)  alloc((size_t)N * 4);
    int*   bsum   = (int*)  alloc((size_t)NB * 4);
    int*   csr    = (int*)  alloc((size_t)(E + N) * 4);
    int*   gstart = (int*)  alloc((size_t)(G + 1) * 4);

    // CSR build (shared by both layers) — hierarchical scan
    init_counts<<<(N + 255) / 256, 256, 0, stream>>>(cursor, N);
    count_edges<<<(E + 255) / 256, 256, 0, stream>>>(dstp, cursor, E);
    block_sums<<<NB, 256, 0, stream>>>(cursor, bsum, N);
    scan_bsums<<<1, 256, 0, stream>>>(bsum, NB);
    scatter_scan<<<NB, 256, 0, stream>>>(cursor, bsum, indptr, cursor, N);
    scatter_edges<<<(E + N + 255) / 256, 256, 0, stream>>>(srcp, dstp, cursor, csr, E, N);
    graph_bounds<<<1, 64, 0, stream>>>(batch, gstart, N, G);

    dim3 ggrid((N + G_ROWS - 1) / G_ROWS, 2);
    int  wgrid = (N * 64 + 255) / 256;

    // layer 1
    gemm128<<<ggrid, 256, 0, stream>>>(x, W1, h, N);
    attn_logits<<<wgrid, 256, 0, stream>>>(h, as1, ad1, als, ald, N);
    gat_aggregate<<<wgrid, 256, 0, stream>>>(h, als, ald, indptr, csr, b1, ob,
                                             nullptr, nullptr, N);
    // layer 2
    gemm128<<<ggrid, 256, 0, stream>>>(ob, W2, h, N);
    attn_logits<<<wgrid, 256, 0, stream>>>(h, as2, ad2, als, ald, N);
    gat_aggregate<<<wgrid, 256, 0, stream>>>(h, als, ald, indptr, csr, b2, nullptr,
                                             Wh, svec, N);
    // pool + head (tiny: 50 blocks x ~1000 scalars)
    pool_reduce<<<G, 256, 0, stream>>>(svec, gstart, bh, out, G);
}

// Round 4
// 404.101 us; speedup vs baseline: 1.8429x; 1.2972x over previous
//
#include <hip/hip_runtime.h>
#include <math.h>

#define HD 128          // hidden dim (= H*C = D_IN)
#define NEG_SLOPE 0.2f
#define EPSV 1e-16f

typedef unsigned short ushort_t;
typedef __attribute__((ext_vector_type(8))) short bf16x8;
typedef __attribute__((ext_vector_type(4))) float f32x4;

// RNE split of fp32 into hi/lo bf16 bit patterns
__device__ inline void bsplit(float x, ushort_t& hi, ushort_t& lo) {
    unsigned u = __float_as_uint(x);
    unsigned hb = (u + 0x7FFFu + ((u >> 16) & 1u)) >> 16;
    hi = (ushort_t)hb;
    float res = x - __uint_as_float(hb << 16);
    unsigned v = __float_as_uint(res);
    lo = (ushort_t)((v + 0x7FFFu + ((v >> 16) & 1u)) >> 16);
}

// ---------------- CSR build ----------------
__global__ void init_counts(int* __restrict__ cnt, int N) {
    int i = blockIdx.x * blockDim.x + threadIdx.x;
    if (i < N) cnt[i] = 1;   // self-loop pre-count
}

__global__ void count_edges(const int* __restrict__ dst, int* __restrict__ cnt, int E) {
    int i = blockIdx.x * blockDim.x + threadIdx.x;
    if (i < E) atomicAdd(&cnt[dst[i]], 1);
}

// hierarchical scan, stage 1: per-256-chunk sums
__global__ __launch_bounds__(256) void block_sums(const int* __restrict__ cnt,
                                                  int* __restrict__ bsum, int N) {
    __shared__ int s[4];
    int t = threadIdx.x;
    int i = blockIdx.x * 256 + t;
    int v = (i < N) ? cnt[i] : 0;
    for (int o = 32; o >= 1; o >>= 1) v += __shfl_xor(v, o, 64);
    if ((t & 63) == 0) s[t >> 6] = v;
    __syncthreads();
    if (t == 0) bsum[blockIdx.x] = s[0] + s[1] + s[2] + s[3];
}

// stage 2: exclusive scan of block sums (single block, tiles of 256 w/ carry)
__global__ __launch_bounds__(256) void scan_bsums(int* __restrict__ bsum, int NB) {
    __shared__ int s[256];
    __shared__ int carry;
    int t = threadIdx.x;
    if (t == 0) carry = 0;
    __syncthreads();
    for (int base = 0; base < NB; base += 256) {
        int i = base + t;
        int v = (i < NB) ? bsum[i] : 0;
        s[t] = v;
        __syncthreads();
        for (int o = 1; o < 256; o <<= 1) {
            int u = (t >= o) ? s[t - o] : 0;
            __syncthreads();
            s[t] += u;
            __syncthreads();
        }
        int excl = ((t == 0) ? 0 : s[t - 1]) + carry;
        if (i < NB) bsum[i] = excl;
        __syncthreads();
        if (t == 0) carry += s[255];
        __syncthreads();
    }
}

// stage 3: in-block exclusive scan + block offset -> indptr & cursor
__global__ __launch_bounds__(256) void scatter_scan(const int* __restrict__ cnt,
                                                    const int* __restrict__ bsum,
                                                    int* __restrict__ indptr,
                                                    int* __restrict__ cursor, int N) {
    __shared__ int s[256];
    int t = threadIdx.x;
    int i = blockIdx.x * 256 + t;
    int v = (i < N) ? cnt[i] : 0;
    s[t] = v;
    __syncthreads();
    for (int o = 1; o < 256; o <<= 1) {
        int u = (t >= o) ? s[t - o] : 0;
        __syncthreads();
        s[t] += u;
        __syncthreads();
    }
    int excl = ((t == 0) ? 0 : s[t - 1]) + bsum[blockIdx.x];
    if (i < N) { indptr[i] = excl; cursor[i] = excl; }
    if (i == N - 1) indptr[N] = excl + v;
}

__global__ void scatter_edges(const int* __restrict__ src, const int* __restrict__ dst,
                              int* __restrict__ cursor, int* __restrict__ csr,
                              int E, int N) {
    int i = blockIdx.x * blockDim.x + threadIdx.x;
    if (i < E) {
        int p = atomicAdd(&cursor[dst[i]], 1);
        csr[p] = src[i];
    } else if (i < E + N) {
        int n = i - E;
        int p = atomicAdd(&cursor[n], 1);
        csr[p] = n;        // self-loop
    }
}

// ---------------- W split+swizzle into MFMA B-fragment order ----------------
// Layout: flat idx = ((ct*4 + ks)*64 + lane)*8 + j
// value  = W[k][n], n = ct*16 + (lane&15), k = ks*32 + (lane>>4)*8 + j
// One lane's 8 ushorts are contiguous -> single 16B load in the GEMM.
__global__ __launch_bounds__(256) void split_w(const float* __restrict__ W,
                                               ushort_t* __restrict__ Whs,
                                               ushort_t* __restrict__ Wls) {
    int idx = blockIdx.x * 256 + threadIdx.x;   // 0..16383
    int j    = idx & 7;
    int lane = (idx >> 3) & 63;
    int ks   = (idx >> 9) & 3;
    int ct   = idx >> 11;
    int n = ct * 16 + (lane & 15);
    int k = ks * 32 + (lane >> 4) * 8 + j;
    ushort_t hi, lo;
    bsplit(W[k * 128 + n], hi, lo);
    Whs[idx] = hi;
    Wls[idx] = lo;
}

// ---------------- GEMM via split-bf16 MFMA: out[N,128] = A[N,128] @ W ----------------
// One wave = 32 rows (2 stacked 16-row tiles). A-frags in regs (loaded once,
// converted inline), W-frags from L1/L2-resident swizzled arrays. No LDS.
__global__ __launch_bounds__(256) void gemm_mfma(const float* __restrict__ A,
                                                 const ushort_t* __restrict__ Whs,
                                                 const ushort_t* __restrict__ Wls,
                                                 float* __restrict__ out, int N) {
    const int gw   = (blockIdx.x * 256 + threadIdx.x) >> 6;
    const int lane = threadIdx.x & 63;
    const int r0   = gw * 32;
    if (r0 >= N) return;
    const int m = lane & 15;
    const int q = lane >> 4;

    // A fragments: ah/al[tile][kstep], tile rows r0 + t*16 + m, k = ks*32 + q*8 + j
    bf16x8 ah[2][4], al[2][4];
    #pragma unroll
    for (int t = 0; t < 2; ++t) {
        int row = r0 + t * 16 + m;
        if (row >= N) row = N - 1;      // safe clamp; stores are guarded
        const float* ap = A + (size_t)row * HD;
        #pragma unroll
        for (int ks = 0; ks < 4; ++ks) {
            float4 v0 = *(const float4*)(ap + ks * 32 + q * 8);
            float4 v1 = *(const float4*)(ap + ks * 32 + q * 8 + 4);
            float vv[8] = {v0.x, v0.y, v0.z, v0.w, v1.x, v1.y, v1.z, v1.w};
            #pragma unroll
            for (int j = 0; j < 8; ++j) {
                ushort_t hb, lb;
                bsplit(vv[j], hb, lb);
                ah[t][ks][j] = (short)hb;
                al[t][ks][j] = (short)lb;
            }
        }
    }

    #pragma unroll 1
    for (int ct = 0; ct < 8; ++ct) {
        f32x4 acc0 = {0.f, 0.f, 0.f, 0.f};
        f32x4 acc1 = {0.f, 0.f, 0.f, 0.f};
        #pragma unroll
        for (int ks = 0; ks < 4; ++ks) {
            bf16x8 wh = *(const bf16x8*)(Whs + ((size_t)(ct * 4 + ks) * 64 + lane) * 8);
            bf16x8 wl = *(const bf16x8*)(Wls + ((size_t)(ct * 4 + ks) * 64 + lane) * 8);
            acc0 = __builtin_amdgcn_mfma_f32_16x16x32_bf16(ah[0][ks], wh, acc0, 0, 0, 0);
            acc1 = __builtin_amdgcn_mfma_f32_16x16x32_bf16(ah[1][ks], wh, acc1, 0, 0, 0);
            acc0 = __builtin_amdgcn_mfma_f32_16x16x32_bf16(al[0][ks], wh, acc0, 0, 0, 0);
            acc1 = __builtin_amdgcn_mfma_f32_16x16x32_bf16(al[1][ks], wh, acc1, 0, 0, 0);
            acc0 = __builtin_amdgcn_mfma_f32_16x16x32_bf16(ah[0][ks], wl, acc0, 0, 0, 0);
            acc1 = __builtin_amdgcn_mfma_f32_16x16x32_bf16(ah[1][ks], wl, acc1, 0, 0, 0);
        }
        // C/D layout: col = lane&15, row = q*4 + reg
        const int col = ct * 16 + m;
        #pragma unroll
        for (int reg = 0; reg < 4; ++reg) {
            int row0 = r0 + q * 4 + reg;
            if (row0 < N) out[(size_t)row0 * HD + col] = acc0[reg];
            int row1 = row0 + 16;
            if (row1 < N) out[(size_t)row1 * HD + col] = acc1[reg];
        }
    }
}

// ---------------- per-node attention logits ----------------
__global__ __launch_bounds__(256) void attn_logits(const float* __restrict__ h,
                                                   const float* __restrict__ a_s,
                                                   const float* __restrict__ a_d,
                                                   float* __restrict__ als,
                                                   float* __restrict__ ald, int N) {
    int gw   = (blockIdx.x * blockDim.x + threadIdx.x) >> 6;
    int lane = threadIdx.x & 63;
    if (gw >= N) return;
    int c = lane * 2;
    float2 hv = *(const float2*)&h[(size_t)gw * HD + c];
    float s = hv.x * a_s[c] + hv.y * a_s[c + 1];
    float d = hv.x * a_d[c] + hv.y * a_d[c + 1];
    // lanes 0..31 = head0, 32..63 = head1 (xor<=16 stays within half)
    for (int o = 16; o >= 1; o >>= 1) {
        s += __shfl_xor(s, o, 64);
        d += __shfl_xor(d, o, 64);
    }
    if (lane == 0)  { als[2 * gw]     = s; ald[2 * gw]     = d; }
    if (lane == 32) { als[2 * gw + 1] = s; ald[2 * gw + 1] = d; }
}

// ---------------- GAT aggregation: one wave per dst node ----------------
// If svec != nullptr: instead of writing out[], compute s[w] = relu(o)·Wh
// (the mean-pool head is linear, so per-node dot products suffice).
__global__ __launch_bounds__(256) void gat_aggregate(const float* __restrict__ h,
                                                     const float* __restrict__ als,
                                                     const float* __restrict__ ald,
                                                     const int* __restrict__ indptr,
                                                     const int* __restrict__ csr,
                                                     const float* __restrict__ bias,
                                                     float* __restrict__ out,
                                                     const float* __restrict__ Wh,
                                                     float* __restrict__ svec, int N) {
    int w    = (blockIdx.x * blockDim.x + threadIdx.x) >> 6;
    int lane = threadIdx.x & 63;
    if (w >= N) return;
    int start = indptr[w], end = indptr[w + 1];
    float ad0 = ald[2 * w], ad1 = ald[2 * w + 1];

    // pass 1: per-head max of leaky_relu(al_s[src]+al_d[dst])
    float m0 = -INFINITY, m1 = -INFINITY;
    for (int i = start + lane; i < end; i += 64) {
        int s = csr[i];
        float e0 = als[2 * s] + ad0;
        float e1 = als[2 * s + 1] + ad1;
        e0 = e0 > 0.f ? e0 : NEG_SLOPE * e0;
        e1 = e1 > 0.f ? e1 : NEG_SLOPE * e1;
        m0 = fmaxf(m0, e0); m1 = fmaxf(m1, e1);
    }
    for (int o = 32; o >= 1; o >>= 1) {
        m0 = fmaxf(m0, __shfl_xor(m0, o, 64));
        m1 = fmaxf(m1, __shfl_xor(m1, o, 64));
    }

    // pass 2: acc = sum exp(e-m)*h[src]; denom = sum exp(e-m)
    float accx = 0.f, accy = 0.f, d0 = 0.f, d1 = 0.f;
    const int cbase = lane * 2;   // lane<32 -> head0 channels, lane>=32 -> head1
    for (int base = start; base < end; base += 64) {
        int i = base + lane;
        float w0 = 0.f, w1 = 0.f; int s = 0;
        if (i < end) {
            s = csr[i];
            float e0 = als[2 * s] + ad0;
            float e1 = als[2 * s + 1] + ad1;
            e0 = e0 > 0.f ? e0 : NEG_SLOPE * e0;
            e1 = e1 > 0.f ? e1 : NEG_SLOPE * e1;
            w0 = __expf(e0 - m0);
            w1 = __expf(e1 - m1);
        }
        d0 += w0; d1 += w1;
        int nl = end - base; if (nl > 64) nl = 64;
        for (int j = 0; j < nl; ++j) {
            int   sj  = __shfl(s,  j, 64);
            float wj0 = __shfl(w0, j, 64);
            float wj1 = __shfl(w1, j, 64);
            float wj = (lane < 32) ? wj0 : wj1;
            float2 hv = *(const float2*)&h[(size_t)sj * HD + cbase];
            accx += wj * hv.x;
            accy += wj * hv.y;
        }
    }
    for (int o = 32; o >= 1; o >>= 1) {
        d0 += __shfl_xor(d0, o, 64);
        d1 += __shfl_xor(d1, o, 64);
    }
    float D = ((lane < 32) ? d0 : d1) + EPSV;
    float ox = accx / D + bias[cbase];
    float oy = accy / D + bias[cbase + 1];
    ox = ox > 0.f ? ox : 0.f;   // ReLU
    oy = oy > 0.f ? oy : 0.f;

    if (svec) {
        float2 wv = *(const float2*)&Wh[cbase];
        float part = ox * wv.x + oy * wv.y;
        for (int o = 32; o >= 1; o >>= 1) part += __shfl_xor(part, o, 64);
        if (lane == 0) svec[w] = part;
    } else {
        *(float2*)&out[(size_t)w * HD + cbase] = make_float2(ox, oy);
    }
}

// ---------------- graph boundaries (batch is sorted) ----------------
__global__ void graph_bounds(const int* __restrict__ batch, int* __restrict__ gstart,
                             int N, int G) {
    int g = blockIdx.x * blockDim.x + threadIdx.x;
    if (g > G) return;
    int lo = 0, hi = N;
    while (lo < hi) {
        int mid = (lo + hi) >> 1;
        if (batch[mid] < g) lo = mid + 1; else hi = mid;
    }
    gstart[g] = lo;
}

// ---------------- per-graph reduce of per-node head dots ----------------
__global__ __launch_bounds__(256) void pool_reduce(const float* __restrict__ s,
                                                   const int* __restrict__ gstart,
                                                   const float* __restrict__ bh,
                                                   float* __restrict__ out, int G) {
    __shared__ float partial[4];
    int g = blockIdx.x, t = threadIdx.x;
    int a = gstart[g], b = gstart[g + 1];
    float sum = 0.f;
    for (int i = a + t; i < b; i += 256) sum += s[i];
    for (int o = 32; o >= 1; o >>= 1) sum += __shfl_xor(sum, o, 64);
    if ((t & 63) == 0) partial[t >> 6] = sum;
    __syncthreads();
    if (t == 0) {
        float cnt = (float)(b - a); if (cnt < 1.f) cnt = 1.f;
        out[g] = (partial[0] + partial[1] + partial[2] + partial[3]) / cnt + bh[0];
    }
}

// ---------------- launch ----------------
extern "C" void kernel_launch(void* const* d_in, const int* in_sizes, int n_in,
                              void* d_out, int out_size, void* d_ws, size_t ws_size,
                              hipStream_t stream) {
    const float* x     = (const float*)d_in[0];
    const int*   ei    = (const int*)d_in[1];
    const int*   batch = (const int*)d_in[2];
    const float* W1  = (const float*)d_in[3];
    const float* as1 = (const float*)d_in[4];
    const float* ad1 = (const float*)d_in[5];
    const float* b1  = (const float*)d_in[6];
    const float* W2  = (const float*)d_in[7];
    const float* as2 = (const float*)d_in[8];
    const float* ad2 = (const float*)d_in[9];
    const float* b2  = (const float*)d_in[10];
    const float* Wh  = (const float*)d_in[11];
    const float* bh  = (const float*)d_in[12];
    float* out = (float*)d_out;

    const int N = in_sizes[0] / HD;
    const int E = in_sizes[1] / 2;
    const int G = out_size;
    const int* srcp = ei;
    const int* dstp = ei + E;
    const int NB = (N + 255) / 256;

    char* ws = (char*)d_ws;
    size_t off = 0;
    auto alloc = [&](size_t bytes) -> void* {
        void* p = ws + off;
        off += (bytes + 255) & ~(size_t)255;
        return p;
    };
    float* h      = (float*)alloc((size_t)N * HD * 4);
    float* ob     = (float*)alloc((size_t)N * HD * 4);
    float* als    = (float*)alloc((size_t)N * 2 * 4);
    float* ald    = (float*)alloc((size_t)N * 2 * 4);
    float* svec   = (float*)alloc((size_t)N * 4);
    int*   indptr = (int*)  alloc((size_t)(N + 1) * 4);
    int*   cursor = (int*)  alloc((size_t)N * 4);
    int*   bsum   = (int*)  alloc((size_t)NB * 4);
    int*   csr    = (int*)  alloc((size_t)(E + N) * 4);
    int*   gstart = (int*)  alloc((size_t)(G + 1) * 4);
    ushort_t* Whs1 = (ushort_t*)alloc(16384 * 2);
    ushort_t* Wls1 = (ushort_t*)alloc(16384 * 2);
    ushort_t* Whs2 = (ushort_t*)alloc(16384 * 2);
    ushort_t* Wls2 = (ushort_t*)alloc(16384 * 2);

    // CSR build (shared by both layers) — hierarchical scan
    init_counts<<<(N + 255) / 256, 256, 0, stream>>>(cursor, N);
    count_edges<<<(E + 255) / 256, 256, 0, stream>>>(dstp, cursor, E);
    block_sums<<<NB, 256, 0, stream>>>(cursor, bsum, N);
    scan_bsums<<<1, 256, 0, stream>>>(bsum, NB);
    scatter_scan<<<NB, 256, 0, stream>>>(cursor, bsum, indptr, cursor, N);
    scatter_edges<<<(E + N + 255) / 256, 256, 0, stream>>>(srcp, dstp, cursor, csr, E, N);
    graph_bounds<<<1, 64, 0, stream>>>(batch, gstart, N, G);

    // W split+swizzle (tiny)
    split_w<<<64, 256, 0, stream>>>(W1, Whs1, Wls1);
    split_w<<<64, 256, 0, stream>>>(W2, Whs2, Wls2);

    const int nwaves  = (N + 31) / 32;
    const int gblocks = (nwaves + 3) / 4;
    int wgrid = (N * 64 + 255) / 256;

    // layer 1
    gemm_mfma<<<gblocks, 256, 0, stream>>>(x, Whs1, Wls1, h, N);
    attn_logits<<<wgrid, 256, 0, stream>>>(h, as1, ad1, als, ald, N);
    gat_aggregate<<<wgrid, 256, 0, stream>>>(h, als, ald, indptr, csr, b1, ob,
                                             nullptr, nullptr, N);
    // layer 2
    gemm_mfma<<<gblocks, 256, 0, stream>>>(ob, Whs2, Wls2, h, N);
    attn_logits<<<wgrid, 256, 0, stream>>>(h, as2, ad2, als, ald, N);
    gat_aggregate<<<wgrid, 256, 0, stream>>>(h, als, ald, indptr, csr, b2, nullptr,
                                             Wh, svec, N);
    // pool + head (tiny: 50 blocks x ~1000 scalars)
    pool_reduce<<<G, 256, 0, stream>>>(svec, gstart, bh, out, G);
}

// Round 5
// 359.751 us; speedup vs baseline: 2.0701x; 1.1233x over previous
//
#include <hip/hip_runtime.h>
#include <math.h>

#define HD 128          // hidden dim (= H*C = D_IN)
#define NEG_SLOPE 0.2f
#define EPSV 1e-16f

typedef unsigned short ushort_t;
typedef __attribute__((ext_vector_type(8))) short bf16x8;
typedef __attribute__((ext_vector_type(4))) float f32x4;

// RNE split of fp32 into hi/lo bf16 bit patterns
__device__ inline void bsplit(float x, ushort_t& hi, ushort_t& lo) {
    unsigned u = __float_as_uint(x);
    unsigned hb = (u + 0x7FFFu + ((u >> 16) & 1u)) >> 16;
    hi = (ushort_t)hb;
    float res = x - __uint_as_float(hb << 16);
    unsigned v = __float_as_uint(res);
    lo = (ushort_t)((v + 0x7FFFu + ((v >> 16) & 1u)) >> 16);
}

// ---------------- CSR build ----------------
__global__ void init_counts(int* __restrict__ cnt, int N) {
    int i = blockIdx.x * blockDim.x + threadIdx.x;
    if (i < N) cnt[i] = 1;   // self-loop pre-count
}

__global__ void count_edges(const int* __restrict__ dst, int* __restrict__ cnt, int E) {
    int i = blockIdx.x * blockDim.x + threadIdx.x;
    if (i < E) atomicAdd(&cnt[dst[i]], 1);
}

// hierarchical scan, stage 1: per-256-chunk sums
__global__ __launch_bounds__(256) void block_sums(const int* __restrict__ cnt,
                                                  int* __restrict__ bsum, int N) {
    __shared__ int s[4];
    int t = threadIdx.x;
    int i = blockIdx.x * 256 + t;
    int v = (i < N) ? cnt[i] : 0;
    for (int o = 32; o >= 1; o >>= 1) v += __shfl_xor(v, o, 64);
    if ((t & 63) == 0) s[t >> 6] = v;
    __syncthreads();
    if (t == 0) bsum[blockIdx.x] = s[0] + s[1] + s[2] + s[3];
}

// stage 2: exclusive scan of block sums (single block, tiles of 256 w/ carry)
__global__ __launch_bounds__(256) void scan_bsums(int* __restrict__ bsum, int NB) {
    __shared__ int s[256];
    __shared__ int carry;
    int t = threadIdx.x;
    if (t == 0) carry = 0;
    __syncthreads();
    for (int base = 0; base < NB; base += 256) {
        int i = base + t;
        int v = (i < NB) ? bsum[i] : 0;
        s[t] = v;
        __syncthreads();
        for (int o = 1; o < 256; o <<= 1) {
            int u = (t >= o) ? s[t - o] : 0;
            __syncthreads();
            s[t] += u;
            __syncthreads();
        }
        int excl = ((t == 0) ? 0 : s[t - 1]) + carry;
        if (i < NB) bsum[i] = excl;
        __syncthreads();
        if (t == 0) carry += s[255];
        __syncthreads();
    }
}

// stage 3: in-block exclusive scan + block offset -> indptr & cursor
__global__ __launch_bounds__(256) void scatter_scan(const int* __restrict__ cnt,
                                                    const int* __restrict__ bsum,
                                                    int* __restrict__ indptr,
                                                    int* __restrict__ cursor, int N) {
    __shared__ int s[256];
    int t = threadIdx.x;
    int i = blockIdx.x * 256 + t;
    int v = (i < N) ? cnt[i] : 0;
    s[t] = v;
    __syncthreads();
    for (int o = 1; o < 256; o <<= 1) {
        int u = (t >= o) ? s[t - o] : 0;
        __syncthreads();
        s[t] += u;
        __syncthreads();
    }
    int excl = ((t == 0) ? 0 : s[t - 1]) + bsum[blockIdx.x];
    if (i < N) { indptr[i] = excl; cursor[i] = excl; }
    if (i == N - 1) indptr[N] = excl + v;
}

__global__ void scatter_edges(const int* __restrict__ src, const int* __restrict__ dst,
                              int* __restrict__ cursor, int* __restrict__ csr,
                              int E, int N) {
    int i = blockIdx.x * blockDim.x + threadIdx.x;
    if (i < E) {
        int p = atomicAdd(&cursor[dst[i]], 1);
        csr[p] = src[i];
    } else if (i < E + N) {
        int n = i - E;
        int p = atomicAdd(&cursor[n], 1);
        csr[p] = n;        // self-loop
    }
}

// ---------------- W split+swizzle into MFMA B-fragment order ----------------
// flat idx = ((ct*4 + ks)*64 + lane)*8 + j ; value = W[k][n],
// n = ct*16 + (lane&15), k = ks*32 + (lane>>4)*8 + j
__global__ __launch_bounds__(256) void split_w(const float* __restrict__ W,
                                               ushort_t* __restrict__ Whs,
                                               ushort_t* __restrict__ Wls) {
    int idx = blockIdx.x * 256 + threadIdx.x;   // 0..16383
    int j    = idx & 7;
    int lane = (idx >> 3) & 63;
    int ks   = (idx >> 9) & 3;
    int ct   = idx >> 11;
    int n = ct * 16 + (lane & 15);
    int k = ks * 32 + (lane >> 4) * 8 + j;
    ushort_t hi, lo;
    bsplit(W[k * 128 + n], hi, lo);
    Whs[idx] = hi;
    Wls[idx] = lo;
}

// ---------------- GEMM via split-bf16 MFMA + fused attention logits ----------------
// One wave = 32 rows. A-frags in regs; W-frags L1/L2-resident. Epilogue also
// computes als/ald (per-head dot with a_s/a_d) via 16-lane xor reductions.
__global__ __launch_bounds__(256) void gemm_mfma(const float* __restrict__ A,
                                                 const ushort_t* __restrict__ Whs,
                                                 const ushort_t* __restrict__ Wls,
                                                 const float* __restrict__ a_s,
                                                 const float* __restrict__ a_d,
                                                 float* __restrict__ out,
                                                 float* __restrict__ als,
                                                 float* __restrict__ ald, int N) {
    const int gw   = (blockIdx.x * 256 + threadIdx.x) >> 6;
    const int lane = threadIdx.x & 63;
    const int r0   = gw * 32;
    if (r0 >= N) return;
    const int m = lane & 15;
    const int q = lane >> 4;

    // A fragments
    bf16x8 ah[2][4], al[2][4];
    #pragma unroll
    for (int t = 0; t < 2; ++t) {
        int row = r0 + t * 16 + m;
        if (row >= N) row = N - 1;      // safe clamp; stores are guarded
        const float* ap = A + (size_t)row * HD;
        #pragma unroll
        for (int ks = 0; ks < 4; ++ks) {
            float4 v0 = *(const float4*)(ap + ks * 32 + q * 8);
            float4 v1 = *(const float4*)(ap + ks * 32 + q * 8 + 4);
            float vv[8] = {v0.x, v0.y, v0.z, v0.w, v1.x, v1.y, v1.z, v1.w};
            #pragma unroll
            for (int j = 0; j < 8; ++j) {
                ushort_t hb, lb;
                bsplit(vv[j], hb, lb);
                ah[t][ks][j] = (short)hb;
                al[t][ks][j] = (short)lb;
            }
        }
    }

    float ps[2][4] = {{0,0,0,0},{0,0,0,0}};   // logit partials (current head)
    float pd[2][4] = {{0,0,0,0},{0,0,0,0}};

    #pragma unroll 1
    for (int ct = 0; ct < 8; ++ct) {
        f32x4 acc0 = {0.f, 0.f, 0.f, 0.f};
        f32x4 acc1 = {0.f, 0.f, 0.f, 0.f};
        #pragma unroll
        for (int ks = 0; ks < 4; ++ks) {
            bf16x8 wh = *(const bf16x8*)(Whs + ((size_t)(ct * 4 + ks) * 64 + lane) * 8);
            bf16x8 wl = *(const bf16x8*)(Wls + ((size_t)(ct * 4 + ks) * 64 + lane) * 8);
            acc0 = __builtin_amdgcn_mfma_f32_16x16x32_bf16(ah[0][ks], wh, acc0, 0, 0, 0);
            acc1 = __builtin_amdgcn_mfma_f32_16x16x32_bf16(ah[1][ks], wh, acc1, 0, 0, 0);
            acc0 = __builtin_amdgcn_mfma_f32_16x16x32_bf16(al[0][ks], wh, acc0, 0, 0, 0);
            acc1 = __builtin_amdgcn_mfma_f32_16x16x32_bf16(al[1][ks], wh, acc1, 0, 0, 0);
            acc0 = __builtin_amdgcn_mfma_f32_16x16x32_bf16(ah[0][ks], wl, acc0, 0, 0, 0);
            acc1 = __builtin_amdgcn_mfma_f32_16x16x32_bf16(ah[1][ks], wl, acc1, 0, 0, 0);
        }
        // C/D layout: col = lane&15, row = q*4 + reg
        const int col = ct * 16 + m;
        const float asv = a_s[col], adv = a_d[col];
        #pragma unroll
        for (int reg = 0; reg < 4; ++reg) {
            ps[0][reg] += acc0[reg] * asv;  pd[0][reg] += acc0[reg] * adv;
            ps[1][reg] += acc1[reg] * asv;  pd[1][reg] += acc1[reg] * adv;
            int row0 = r0 + q * 4 + reg;
            if (row0 < N) out[(size_t)row0 * HD + col] = acc0[reg];
            int row1 = row0 + 16;
            if (row1 < N) out[(size_t)row1 * HD + col] = acc1[reg];
        }
        if (ct == 3 || ct == 7) {          // head boundary: reduce over m-lanes, store
            int head = ct >> 2;
            #pragma unroll
            for (int t = 0; t < 2; ++t) {
                #pragma unroll
                for (int reg = 0; reg < 4; ++reg) {
                    float vs = ps[t][reg], vd = pd[t][reg];
                    for (int o = 8; o >= 1; o >>= 1) {
                        vs += __shfl_xor(vs, o, 64);
                        vd += __shfl_xor(vd, o, 64);
                    }
                    if (m == 0) {
                        int row = r0 + t * 16 + q * 4 + reg;
                        if (row < N) { als[2 * row + head] = vs; ald[2 * row + head] = vd; }
                    }
                    ps[t][reg] = 0.f;  pd[t][reg] = 0.f;
                }
            }
        }
    }
}

// ---------------- GAT aggregation: one wave per dst node ----------------
// Single pass (no max-shift: logits are O(few), exp() safe in fp32; softmax
// normalization makes the shift redundant). Gather loop unrolled x8 for MLP.
__global__ __launch_bounds__(256) void gat_aggregate(const float* __restrict__ h,
                                                     const float* __restrict__ als,
                                                     const float* __restrict__ ald,
                                                     const int* __restrict__ indptr,
                                                     const int* __restrict__ csr,
                                                     const float* __restrict__ bias,
                                                     float* __restrict__ out,
                                                     const float* __restrict__ Wh,
                                                     float* __restrict__ svec, int N) {
    int w    = (blockIdx.x * blockDim.x + threadIdx.x) >> 6;
    int lane = threadIdx.x & 63;
    if (w >= N) return;
    int start = indptr[w], end = indptr[w + 1];
    float ad0 = ald[2 * w], ad1 = ald[2 * w + 1];
    const bool head0 = (lane < 32);
    const int cbase = lane * 2;

    float accx = 0.f, accy = 0.f, d0 = 0.f, d1 = 0.f;
    for (int base = start; base < end; base += 64) {
        int i = base + lane;
        float w0 = 0.f, w1 = 0.f; int s = 0;
        if (i < end) {
            s = csr[i];
            float e0 = als[2 * s] + ad0;
            float e1 = als[2 * s + 1] + ad1;
            e0 = e0 > 0.f ? e0 : NEG_SLOPE * e0;
            e1 = e1 > 0.f ? e1 : NEG_SLOPE * e1;
            w0 = __expf(e0);
            w1 = __expf(e1);
        }
        d0 += w0; d1 += w1;
        int nl = end - base; if (nl > 64) nl = 64;
        int j = 0;
        for (; j + 8 <= nl; j += 8) {
            int sj[8]; float wa[8];
            #pragma unroll
            for (int u = 0; u < 8; ++u) {
                sj[u] = __shfl(s, j + u, 64);
                float a = __shfl(w0, j + u, 64);
                float b = __shfl(w1, j + u, 64);
                wa[u] = head0 ? a : b;
            }
            float2 hv[8];
            #pragma unroll
            for (int u = 0; u < 8; ++u)
                hv[u] = *(const float2*)&h[(size_t)sj[u] * HD + cbase];
            #pragma unroll
            for (int u = 0; u < 8; ++u) {
                accx += wa[u] * hv[u].x;
                accy += wa[u] * hv[u].y;
            }
        }
        for (; j < nl; ++j) {
            int sjv = __shfl(s, j, 64);
            float a = __shfl(w0, j, 64);
            float b = __shfl(w1, j, 64);
            float wj = head0 ? a : b;
            float2 hv = *(const float2*)&h[(size_t)sjv * HD + cbase];
            accx += wj * hv.x;
            accy += wj * hv.y;
        }
    }
    for (int o = 32; o >= 1; o >>= 1) {
        d0 += __shfl_xor(d0, o, 64);
        d1 += __shfl_xor(d1, o, 64);
    }
    float D = (head0 ? d0 : d1) + EPSV;
    float ox = accx / D + bias[cbase];
    float oy = accy / D + bias[cbase + 1];
    ox = ox > 0.f ? ox : 0.f;   // ReLU
    oy = oy > 0.f ? oy : 0.f;

    if (svec) {
        float2 wv = *(const float2*)&Wh[cbase];
        float part = ox * wv.x + oy * wv.y;
        for (int o = 32; o >= 1; o >>= 1) part += __shfl_xor(part, o, 64);
        if (lane == 0) svec[w] = part;
    } else {
        *(float2*)&out[(size_t)w * HD + cbase] = make_float2(ox, oy);
    }
}

// ---------------- graph boundaries (batch is sorted) ----------------
__global__ void graph_bounds(const int* __restrict__ batch, int* __restrict__ gstart,
                             int N, int G) {
    int g = blockIdx.x * blockDim.x + threadIdx.x;
    if (g > G) return;
    int lo = 0, hi = N;
    while (lo < hi) {
        int mid = (lo + hi) >> 1;
        if (batch[mid] < g) lo = mid + 1; else hi = mid;
    }
    gstart[g] = lo;
}

// ---------------- per-graph reduce of per-node head dots ----------------
__global__ __launch_bounds__(256) void pool_reduce(const float* __restrict__ s,
                                                   const int* __restrict__ gstart,
                                                   const float* __restrict__ bh,
                                                   float* __restrict__ out, int G) {
    __shared__ float partial[4];
    int g = blockIdx.x, t = threadIdx.x;
    int a = gstart[g], b = gstart[g + 1];
    float sum = 0.f;
    for (int i = a + t; i < b; i += 256) sum += s[i];
    for (int o = 32; o >= 1; o >>= 1) sum += __shfl_xor(sum, o, 64);
    if ((t & 63) == 0) partial[t >> 6] = sum;
    __syncthreads();
    if (t == 0) {
        float cnt = (float)(b - a); if (cnt < 1.f) cnt = 1.f;
        out[g] = (partial[0] + partial[1] + partial[2] + partial[3]) / cnt + bh[0];
    }
}

// ---------------- launch ----------------
extern "C" void kernel_launch(void* const* d_in, const int* in_sizes, int n_in,
                              void* d_out, int out_size, void* d_ws, size_t ws_size,
                              hipStream_t stream) {
    const float* x     = (const float*)d_in[0];
    const int*   ei    = (const int*)d_in[1];
    const int*   batch = (const int*)d_in[2];
    const float* W1  = (const float*)d_in[3];
    const float* as1 = (const float*)d_in[4];
    const float* ad1 = (const float*)d_in[5];
    const float* b1  = (const float*)d_in[6];
    const float* W2  = (const float*)d_in[7];
    const float* as2 = (const float*)d_in[8];
    const float* ad2 = (const float*)d_in[9];
    const float* b2  = (const float*)d_in[10];
    const float* Wh  = (const float*)d_in[11];
    const float* bh  = (const float*)d_in[12];
    float* out = (float*)d_out;

    const int N = in_sizes[0] / HD;
    const int E = in_sizes[1] / 2;
    const int G = out_size;
    const int* srcp = ei;
    const int* dstp = ei + E;
    const int NB = (N + 255) / 256;

    char* ws = (char*)d_ws;
    size_t off = 0;
    auto alloc = [&](size_t bytes) -> void* {
        void* p = ws + off;
        off += (bytes + 255) & ~(size_t)255;
        return p;
    };
    float* h      = (float*)alloc((size_t)N * HD * 4);
    float* ob     = (float*)alloc((size_t)N * HD * 4);
    float* als    = (float*)alloc((size_t)N * 2 * 4);
    float* ald    = (float*)alloc((size_t)N * 2 * 4);
    float* svec   = (float*)alloc((size_t)N * 4);
    int*   indptr = (int*)  alloc((size_t)(N + 1) * 4);
    int*   cursor = (int*)  alloc((size_t)N * 4);
    int*   bsum   = (int*)  alloc((size_t)NB * 4);
    int*   csr    = (int*)  alloc((size_t)(E + N) * 4);
    int*   gstart = (int*)  alloc((size_t)(G + 1) * 4);
    ushort_t* Whs1 = (ushort_t*)alloc(16384 * 2);
    ushort_t* Wls1 = (ushort_t*)alloc(16384 * 2);
    ushort_t* Whs2 = (ushort_t*)alloc(16384 * 2);
    ushort_t* Wls2 = (ushort_t*)alloc(16384 * 2);

    // CSR build (shared by both layers) — hierarchical scan
    init_counts<<<(N + 255) / 256, 256, 0, stream>>>(cursor, N);
    count_edges<<<(E + 255) / 256, 256, 0, stream>>>(dstp, cursor, E);
    block_sums<<<NB, 256, 0, stream>>>(cursor, bsum, N);
    scan_bsums<<<1, 256, 0, stream>>>(bsum, NB);
    scatter_scan<<<NB, 256, 0, stream>>>(cursor, bsum, indptr, cursor, N);
    scatter_edges<<<(E + N + 255) / 256, 256, 0, stream>>>(srcp, dstp, cursor, csr, E, N);
    graph_bounds<<<1, 64, 0, stream>>>(batch, gstart, N, G);

    // W split+swizzle (tiny)
    split_w<<<64, 256, 0, stream>>>(W1, Whs1, Wls1);
    split_w<<<64, 256, 0, stream>>>(W2, Whs2, Wls2);

    const int nwaves  = (N + 31) / 32;
    const int gblocks = (nwaves + 3) / 4;
    int wgrid = (N * 64 + 255) / 256;

    // layer 1 (logits fused into GEMM epilogue)
    gemm_mfma<<<gblocks, 256, 0, stream>>>(x, Whs1, Wls1, as1, ad1, h, als, ald, N);
    gat_aggregate<<<wgrid, 256, 0, stream>>>(h, als, ald, indptr, csr, b1, ob,
                                             nullptr, nullptr, N);
    // layer 2
    gemm_mfma<<<gblocks, 256, 0, stream>>>(ob, Whs2, Wls2, as2, ad2, h, als, ald, N);
    gat_aggregate<<<wgrid, 256, 0, stream>>>(h, als, ald, indptr, csr, b2, nullptr,
                                             Wh, svec, N);
    // pool + head (tiny: 50 blocks x ~1000 scalars)
    pool_reduce<<<G, 256, 0, stream>>>(svec, gstart, bh, out, G);
}

// Round 6
// 327.833 us; speedup vs baseline: 2.2716x; 1.0974x over previous
//
#include <hip/hip_runtime.h>
#include <hip/hip_fp16.h>
#include <math.h>

#define HD 128          // hidden dim (= H*C = D_IN)
#define NEG_SLOPE 0.2f
#define EPSV 1e-16f

typedef unsigned short ushort_t;
typedef __attribute__((ext_vector_type(8))) short bf16x8;
typedef __attribute__((ext_vector_type(4))) float f32x4;

// RNE split of fp32 into hi/lo bf16 bit patterns
__device__ inline void bsplit(float x, ushort_t& hi, ushort_t& lo) {
    unsigned u = __float_as_uint(x);
    unsigned hb = (u + 0x7FFFu + ((u >> 16) & 1u)) >> 16;
    hi = (ushort_t)hb;
    float res = x - __uint_as_float(hb << 16);
    unsigned v = __float_as_uint(res);
    lo = (ushort_t)((v + 0x7FFFu + ((v >> 16) & 1u)) >> 16);
}

// ---------------- CSR build ----------------
__global__ void init_counts(int* __restrict__ cnt, int N) {
    int i = blockIdx.x * blockDim.x + threadIdx.x;
    if (i < N) cnt[i] = 1;   // self-loop pre-count
}

__global__ void count_edges(const int* __restrict__ dst, int* __restrict__ cnt, int E) {
    int i = blockIdx.x * blockDim.x + threadIdx.x;
    if (i < E) atomicAdd(&cnt[dst[i]], 1);
}

// hierarchical scan, stage 1: per-256-chunk sums
__global__ __launch_bounds__(256) void block_sums(const int* __restrict__ cnt,
                                                  int* __restrict__ bsum, int N) {
    __shared__ int s[4];
    int t = threadIdx.x;
    int i = blockIdx.x * 256 + t;
    int v = (i < N) ? cnt[i] : 0;
    for (int o = 32; o >= 1; o >>= 1) v += __shfl_xor(v, o, 64);
    if ((t & 63) == 0) s[t >> 6] = v;
    __syncthreads();
    if (t == 0) bsum[blockIdx.x] = s[0] + s[1] + s[2] + s[3];
}

// stage 2: exclusive scan of block sums (single block, tiles of 256 w/ carry)
__global__ __launch_bounds__(256) void scan_bsums(int* __restrict__ bsum, int NB) {
    __shared__ int s[256];
    __shared__ int carry;
    int t = threadIdx.x;
    if (t == 0) carry = 0;
    __syncthreads();
    for (int base = 0; base < NB; base += 256) {
        int i = base + t;
        int v = (i < NB) ? bsum[i] : 0;
        s[t] = v;
        __syncthreads();
        for (int o = 1; o < 256; o <<= 1) {
            int u = (t >= o) ? s[t - o] : 0;
            __syncthreads();
            s[t] += u;
            __syncthreads();
        }
        int excl = ((t == 0) ? 0 : s[t - 1]) + carry;
        if (i < NB) bsum[i] = excl;
        __syncthreads();
        if (t == 0) carry += s[255];
        __syncthreads();
    }
}

// stage 3: in-block exclusive scan + block offset -> indptr & cursor
__global__ __launch_bounds__(256) void scatter_scan(const int* __restrict__ cnt,
                                                    const int* __restrict__ bsum,
                                                    int* __restrict__ indptr,
                                                    int* __restrict__ cursor, int N) {
    __shared__ int s[256];
    int t = threadIdx.x;
    int i = blockIdx.x * 256 + t;
    int v = (i < N) ? cnt[i] : 0;
    s[t] = v;
    __syncthreads();
    for (int o = 1; o < 256; o <<= 1) {
        int u = (t >= o) ? s[t - o] : 0;
        __syncthreads();
        s[t] += u;
        __syncthreads();
    }
    int excl = ((t == 0) ? 0 : s[t - 1]) + bsum[blockIdx.x];
    if (i < N) { indptr[i] = excl; cursor[i] = excl; }
    if (i == N - 1) indptr[N] = excl + v;
}

__global__ void scatter_edges(const int* __restrict__ src, const int* __restrict__ dst,
                              int* __restrict__ cursor, int* __restrict__ csr,
                              int E, int N) {
    int i = blockIdx.x * blockDim.x + threadIdx.x;
    if (i < E) {
        int p = atomicAdd(&cursor[dst[i]], 1);
        csr[p] = src[i];
    } else if (i < E + N) {
        int n = i - E;
        int p = atomicAdd(&cursor[n], 1);
        csr[p] = n;        // self-loop
    }
}

// ---------------- W split+swizzle into MFMA B-fragment order ----------------
// flat idx = ((ct*4 + ks)*64 + lane)*8 + j ; value = W[k][n],
// n = ct*16 + (lane&15), k = ks*32 + (lane>>4)*8 + j
__global__ __launch_bounds__(256) void split_w(const float* __restrict__ W,
                                               ushort_t* __restrict__ Whs,
                                               ushort_t* __restrict__ Wls) {
    int idx = blockIdx.x * 256 + threadIdx.x;   // 0..16383
    int j    = idx & 7;
    int lane = (idx >> 3) & 63;
    int ks   = (idx >> 9) & 3;
    int ct   = idx >> 11;
    int n = ct * 16 + (lane & 15);
    int k = ks * 32 + (lane >> 4) * 8 + j;
    ushort_t hi, lo;
    bsplit(W[k * 128 + n], hi, lo);
    Whs[idx] = hi;
    Wls[idx] = lo;
}

// ---------------- GEMM via split-bf16 MFMA + fused attention logits ----------------
// One wave = 32 rows. A-frags in regs; W-frags L1/L2-resident. Output h is
// written in FP16 (only the edge-gather reads it; halves gather traffic).
// Epilogue also computes als/ald via 16-lane xor reductions (fp32 accs).
__global__ __launch_bounds__(256) void gemm_mfma(const float* __restrict__ A,
                                                 const ushort_t* __restrict__ Whs,
                                                 const ushort_t* __restrict__ Wls,
                                                 const float* __restrict__ a_s,
                                                 const float* __restrict__ a_d,
                                                 __half* __restrict__ h16,
                                                 float* __restrict__ als,
                                                 float* __restrict__ ald, int N) {
    const int gw   = (blockIdx.x * 256 + threadIdx.x) >> 6;
    const int lane = threadIdx.x & 63;
    const int r0   = gw * 32;
    if (r0 >= N) return;
    const int m = lane & 15;
    const int q = lane >> 4;

    // A fragments
    bf16x8 ah[2][4], al[2][4];
    #pragma unroll
    for (int t = 0; t < 2; ++t) {
        int row = r0 + t * 16 + m;
        if (row >= N) row = N - 1;      // safe clamp; stores are guarded
        const float* ap = A + (size_t)row * HD;
        #pragma unroll
        for (int ks = 0; ks < 4; ++ks) {
            float4 v0 = *(const float4*)(ap + ks * 32 + q * 8);
            float4 v1 = *(const float4*)(ap + ks * 32 + q * 8 + 4);
            float vv[8] = {v0.x, v0.y, v0.z, v0.w, v1.x, v1.y, v1.z, v1.w};
            #pragma unroll
            for (int j = 0; j < 8; ++j) {
                ushort_t hb, lb;
                bsplit(vv[j], hb, lb);
                ah[t][ks][j] = (short)hb;
                al[t][ks][j] = (short)lb;
            }
        }
    }

    float ps[2][4] = {{0,0,0,0},{0,0,0,0}};   // logit partials (current head)
    float pd[2][4] = {{0,0,0,0},{0,0,0,0}};

    #pragma unroll 1
    for (int ct = 0; ct < 8; ++ct) {
        f32x4 acc0 = {0.f, 0.f, 0.f, 0.f};
        f32x4 acc1 = {0.f, 0.f, 0.f, 0.f};
        #pragma unroll
        for (int ks = 0; ks < 4; ++ks) {
            bf16x8 wh = *(const bf16x8*)(Whs + ((size_t)(ct * 4 + ks) * 64 + lane) * 8);
            bf16x8 wl = *(const bf16x8*)(Wls + ((size_t)(ct * 4 + ks) * 64 + lane) * 8);
            acc0 = __builtin_amdgcn_mfma_f32_16x16x32_bf16(ah[0][ks], wh, acc0, 0, 0, 0);
            acc1 = __builtin_amdgcn_mfma_f32_16x16x32_bf16(ah[1][ks], wh, acc1, 0, 0, 0);
            acc0 = __builtin_amdgcn_mfma_f32_16x16x32_bf16(al[0][ks], wh, acc0, 0, 0, 0);
            acc1 = __builtin_amdgcn_mfma_f32_16x16x32_bf16(al[1][ks], wh, acc1, 0, 0, 0);
            acc0 = __builtin_amdgcn_mfma_f32_16x16x32_bf16(ah[0][ks], wl, acc0, 0, 0, 0);
            acc1 = __builtin_amdgcn_mfma_f32_16x16x32_bf16(ah[1][ks], wl, acc1, 0, 0, 0);
        }
        // C/D layout: col = lane&15, row = q*4 + reg
        const int col = ct * 16 + m;
        const float asv = a_s[col], adv = a_d[col];
        #pragma unroll
        for (int reg = 0; reg < 4; ++reg) {
            ps[0][reg] += acc0[reg] * asv;  pd[0][reg] += acc0[reg] * adv;
            ps[1][reg] += acc1[reg] * asv;  pd[1][reg] += acc1[reg] * adv;
            int row0 = r0 + q * 4 + reg;
            if (row0 < N) h16[(size_t)row0 * HD + col] = __float2half(acc0[reg]);
            int row1 = row0 + 16;
            if (row1 < N) h16[(size_t)row1 * HD + col] = __float2half(acc1[reg]);
        }
        if (ct == 3 || ct == 7) {          // head boundary: reduce over m-lanes, store
            int head = ct >> 2;
            #pragma unroll
            for (int t = 0; t < 2; ++t) {
                #pragma unroll
                for (int reg = 0; reg < 4; ++reg) {
                    float vs = ps[t][reg], vd = pd[t][reg];
                    for (int o = 8; o >= 1; o >>= 1) {
                        vs += __shfl_xor(vs, o, 64);
                        vd += __shfl_xor(vd, o, 64);
                    }
                    if (m == 0) {
                        int row = r0 + t * 16 + q * 4 + reg;
                        if (row < N) { als[2 * row + head] = vs; ald[2 * row + head] = vd; }
                    }
                    ps[t][reg] = 0.f;  pd[t][reg] = 0.f;
                }
            }
        }
    }
}

// ---------------- GAT aggregation: one wave per dst node ----------------
// Single pass, fp16 h gather (256 B/edge), x8-unrolled for MLP.
__global__ __launch_bounds__(256) void gat_aggregate(const __half* __restrict__ h,
                                                     const float* __restrict__ als,
                                                     const float* __restrict__ ald,
                                                     const int* __restrict__ indptr,
                                                     const int* __restrict__ csr,
                                                     const float* __restrict__ bias,
                                                     float* __restrict__ out,
                                                     const float* __restrict__ Wh,
                                                     float* __restrict__ svec, int N) {
    int w    = (blockIdx.x * blockDim.x + threadIdx.x) >> 6;
    int lane = threadIdx.x & 63;
    if (w >= N) return;
    int start = indptr[w], end = indptr[w + 1];
    float ad0 = ald[2 * w], ad1 = ald[2 * w + 1];
    const bool head0 = (lane < 32);
    const int cbase = lane * 2;

    float accx = 0.f, accy = 0.f, d0 = 0.f, d1 = 0.f;
    for (int base = start; base < end; base += 64) {
        int i = base + lane;
        float w0 = 0.f, w1 = 0.f; int s = 0;
        if (i < end) {
            s = csr[i];
            float2 av = *(const float2*)&als[2 * s];
            float e0 = av.x + ad0;
            float e1 = av.y + ad1;
            e0 = e0 > 0.f ? e0 : NEG_SLOPE * e0;
            e1 = e1 > 0.f ? e1 : NEG_SLOPE * e1;
            w0 = __expf(e0);
            w1 = __expf(e1);
        }
        d0 += w0; d1 += w1;
        int nl = end - base; if (nl > 64) nl = 64;
        int j = 0;
        for (; j + 8 <= nl; j += 8) {
            int sj[8]; float wa[8];
            #pragma unroll
            for (int u = 0; u < 8; ++u) {
                sj[u] = __shfl(s, j + u, 64);
                float a = __shfl(w0, j + u, 64);
                float b = __shfl(w1, j + u, 64);
                wa[u] = head0 ? a : b;
            }
            __half2 hv[8];
            #pragma unroll
            for (int u = 0; u < 8; ++u)
                hv[u] = *(const __half2*)&h[(size_t)sj[u] * HD + cbase];
            #pragma unroll
            for (int u = 0; u < 8; ++u) {
                float2 f = __half22float2(hv[u]);
                accx += wa[u] * f.x;
                accy += wa[u] * f.y;
            }
        }
        for (; j < nl; ++j) {
            int sjv = __shfl(s, j, 64);
            float a = __shfl(w0, j, 64);
            float b = __shfl(w1, j, 64);
            float wj = head0 ? a : b;
            float2 f = __half22float2(*(const __half2*)&h[(size_t)sjv * HD + cbase]);
            accx += wj * f.x;
            accy += wj * f.y;
        }
    }
    for (int o = 32; o >= 1; o >>= 1) {
        d0 += __shfl_xor(d0, o, 64);
        d1 += __shfl_xor(d1, o, 64);
    }
    float D = (head0 ? d0 : d1) + EPSV;
    float ox = accx / D + bias[cbase];
    float oy = accy / D + bias[cbase + 1];
    ox = ox > 0.f ? ox : 0.f;   // ReLU
    oy = oy > 0.f ? oy : 0.f;

    if (svec) {
        float2 wv = *(const float2*)&Wh[cbase];
        float part = ox * wv.x + oy * wv.y;
        for (int o = 32; o >= 1; o >>= 1) part += __shfl_xor(part, o, 64);
        if (lane == 0) svec[w] = part;
    } else {
        *(float2*)&out[(size_t)w * HD + cbase] = make_float2(ox, oy);
    }
}

// ---------------- graph boundaries (batch is sorted) ----------------
__global__ void graph_bounds(const int* __restrict__ batch, int* __restrict__ gstart,
                             int N, int G) {
    int g = blockIdx.x * blockDim.x + threadIdx.x;
    if (g > G) return;
    int lo = 0, hi = N;
    while (lo < hi) {
        int mid = (lo + hi) >> 1;
        if (batch[mid] < g) lo = mid + 1; else hi = mid;
    }
    gstart[g] = lo;
}

// ---------------- per-graph reduce of per-node head dots ----------------
__global__ __launch_bounds__(256) void pool_reduce(const float* __restrict__ s,
                                                   const int* __restrict__ gstart,
                                                   const float* __restrict__ bh,
                                                   float* __restrict__ out, int G) {
    __shared__ float partial[4];
    int g = blockIdx.x, t = threadIdx.x;
    int a = gstart[g], b = gstart[g + 1];
    float sum = 0.f;
    for (int i = a + t; i < b; i += 256) sum += s[i];
    for (int o = 32; o >= 1; o >>= 1) sum += __shfl_xor(sum, o, 64);
    if ((t & 63) == 0) partial[t >> 6] = sum;
    __syncthreads();
    if (t == 0) {
        float cnt = (float)(b - a); if (cnt < 1.f) cnt = 1.f;
        out[g] = (partial[0] + partial[1] + partial[2] + partial[3]) / cnt + bh[0];
    }
}

// ---------------- launch ----------------
extern "C" void kernel_launch(void* const* d_in, const int* in_sizes, int n_in,
                              void* d_out, int out_size, void* d_ws, size_t ws_size,
                              hipStream_t stream) {
    const float* x     = (const float*)d_in[0];
    const int*   ei    = (const int*)d_in[1];
    const int*   batch = (const int*)d_in[2];
    const float* W1  = (const float*)d_in[3];
    const float* as1 = (const float*)d_in[4];
    const float* ad1 = (const float*)d_in[5];
    const float* b1  = (const float*)d_in[6];
    const float* W2  = (const float*)d_in[7];
    const float* as2 = (const float*)d_in[8];
    const float* ad2 = (const float*)d_in[9];
    const float* b2  = (const float*)d_in[10];
    const float* Wh  = (const float*)d_in[11];
    const float* bh  = (const float*)d_in[12];
    float* out = (float*)d_out;

    const int N = in_sizes[0] / HD;
    const int E = in_sizes[1] / 2;
    const int G = out_size;
    const int* srcp = ei;
    const int* dstp = ei + E;
    const int NB = (N + 255) / 256;

    char* ws = (char*)d_ws;
    size_t off = 0;
    auto alloc = [&](size_t bytes) -> void* {
        void* p = ws + off;
        off += (bytes + 255) & ~(size_t)255;
        return p;
    };
    __half* h16   = (__half*)alloc((size_t)N * HD * 2);
    float* ob     = (float*)alloc((size_t)N * HD * 4);
    float* als    = (float*)alloc((size_t)N * 2 * 4);
    float* ald    = (float*)alloc((size_t)N * 2 * 4);
    float* svec   = (float*)alloc((size_t)N * 4);
    int*   indptr = (int*)  alloc((size_t)(N + 1) * 4);
    int*   cursor = (int*)  alloc((size_t)N * 4);
    int*   bsum   = (int*)  alloc((size_t)NB * 4);
    int*   csr    = (int*)  alloc((size_t)(E + N) * 4);
    int*   gstart = (int*)  alloc((size_t)(G + 1) * 4);
    ushort_t* Whs1 = (ushort_t*)alloc(16384 * 2);
    ushort_t* Wls1 = (ushort_t*)alloc(16384 * 2);
    ushort_t* Whs2 = (ushort_t*)alloc(16384 * 2);
    ushort_t* Wls2 = (ushort_t*)alloc(16384 * 2);

    // CSR build (shared by both layers) — hierarchical scan
    init_counts<<<(N + 255) / 256, 256, 0, stream>>>(cursor, N);
    count_edges<<<(E + 255) / 256, 256, 0, stream>>>(dstp, cursor, E);
    block_sums<<<NB, 256, 0, stream>>>(cursor, bsum, N);
    scan_bsums<<<1, 256, 0, stream>>>(bsum, NB);
    scatter_scan<<<NB, 256, 0, stream>>>(cursor, bsum, indptr, cursor, N);
    scatter_edges<<<(E + N + 255) / 256, 256, 0, stream>>>(srcp, dstp, cursor, csr, E, N);
    graph_bounds<<<1, 64, 0, stream>>>(batch, gstart, N, G);

    // W split+swizzle (tiny)
    split_w<<<64, 256, 0, stream>>>(W1, Whs1, Wls1);
    split_w<<<64, 256, 0, stream>>>(W2, Whs2, Wls2);

    const int nwaves  = (N + 31) / 32;
    const int gblocks = (nwaves + 3) / 4;
    int wgrid = (N * 64 + 255) / 256;

    // layer 1 (logits fused into GEMM epilogue; h stored fp16)
    gemm_mfma<<<gblocks, 256, 0, stream>>>(x, Whs1, Wls1, as1, ad1, h16, als, ald, N);
    gat_aggregate<<<wgrid, 256, 0, stream>>>(h16, als, ald, indptr, csr, b1, ob,
                                             nullptr, nullptr, N);
    // layer 2
    gemm_mfma<<<gblocks, 256, 0, stream>>>(ob, Whs2, Wls2, as2, ad2, h16, als, ald, N);
    gat_aggregate<<<wgrid, 256, 0, stream>>>(h16, als, ald, indptr, csr, b2, nullptr,
                                             Wh, svec, N);
    // pool + head (tiny: 50 blocks x ~1000 scalars)
    pool_reduce<<<G, 256, 0, stream>>>(svec, gstart, bh, out, G);
}

// Round 7
// 273.022 us; speedup vs baseline: 2.7277x; 1.2008x over previous
//
#include <hip/hip_runtime.h>
#include <hip/hip_fp16.h>
#include <math.h>

#define HD 128          // hidden dim (= H*C = D_IN)
#define NEG_SLOPE 0.2f
#define EPSV 1e-16f
#define TILE 8192       // edges per partition tile

typedef unsigned short ushort_t;
typedef __attribute__((ext_vector_type(8))) short bf16x8;
typedef __attribute__((ext_vector_type(4))) float f32x4;

// RNE split of fp32 into hi/lo bf16 bit patterns
__device__ inline void bsplit(float x, ushort_t& hi, ushort_t& lo) {
    unsigned u = __float_as_uint(x);
    unsigned hb = (u + 0x7FFFu + ((u >> 16) & 1u)) >> 16;
    hi = (ushort_t)hb;
    float res = x - __uint_as_float(hb << 16);
    unsigned v = __float_as_uint(res);
    lo = (ushort_t)((v + 0x7FFFu + ((v >> 16) & 1u)) >> 16);
}

// ---------------- edge partition by coarse bucket (dst>>8) ----------------
__global__ __launch_bounds__(256) void part_hist(const int* __restrict__ dst,
                                                 int* __restrict__ tileHist, int E) {
    __shared__ int hist[256];
    int t = threadIdx.x;
    hist[t] = 0;
    __syncthreads();
    int base = blockIdx.x * TILE;
    int end = base + TILE; if (end > E) end = E;
    for (int i = base + t; i < end; i += 256)
        atomicAdd(&hist[dst[i] >> 8], 1);
    __syncthreads();
    tileHist[blockIdx.x * 256 + t] = hist[t];
}

__global__ __launch_bounds__(256) void part_offsets(int* __restrict__ tileHist,
                                                    int* __restrict__ bucketBase,
                                                    int NT) {
    __shared__ int s[256];
    int b = threadIdx.x;
    int total = 0;
    #pragma unroll 8
    for (int t = 0; t < NT; ++t) total += tileHist[t * 256 + b];
    s[b] = total;
    __syncthreads();
    for (int o = 1; o < 256; o <<= 1) {
        int v = (b >= o) ? s[b - o] : 0;
        __syncthreads();
        s[b] += v;
        __syncthreads();
    }
    int base = (b == 0) ? 0 : s[b - 1];
    bucketBase[b] = base;
    if (b == 255) bucketBase[256] = s[255];
    int run = base;
    #pragma unroll 8
    for (int t = 0; t < NT; ++t) {
        int v = tileHist[t * 256 + b];
        tileHist[t * 256 + b] = run;
        run += v;
    }
}

__global__ __launch_bounds__(256) void part_scatter(const int* __restrict__ src,
                                                    const int* __restrict__ dst,
                                                    const int* __restrict__ tileHist,
                                                    int2* __restrict__ part, int E) {
    __shared__ int cur[256];
    int t = threadIdx.x;
    cur[t] = tileHist[blockIdx.x * 256 + t];
    __syncthreads();
    int base = blockIdx.x * TILE;
    int end = base + TILE; if (end > E) end = E;
    for (int i = base + t; i < end; i += 256) {
        int d = dst[i], s = src[i];
        int p = atomicAdd(&cur[d >> 8], 1);
        part[p] = make_int2(s, d);
    }
}

// per-node counts from partitioned edges (+1 for self-loop)
__global__ __launch_bounds__(256) void fine_counts(const int2* __restrict__ part,
                                                   const int* __restrict__ bucketBase,
                                                   int* __restrict__ cnt, int N) {
    __shared__ int hist[256];
    int t = threadIdx.x;
    hist[t] = 0;
    __syncthreads();
    int b = blockIdx.x;
    int s0 = bucketBase[b], s1 = bucketBase[b + 1];
    for (int i = s0 + t; i < s1; i += 256)
        atomicAdd(&hist[part[i].y & 255], 1);
    __syncthreads();
    int d = b * 256 + t;
    if (d < N) cnt[d] = hist[t] + 1;
}

// hierarchical scan, stage 1: per-256-chunk sums
__global__ __launch_bounds__(256) void block_sums(const int* __restrict__ cnt,
                                                  int* __restrict__ bsum, int N) {
    __shared__ int s[4];
    int t = threadIdx.x;
    int i = blockIdx.x * 256 + t;
    int v = (i < N) ? cnt[i] : 0;
    for (int o = 32; o >= 1; o >>= 1) v += __shfl_xor(v, o, 64);
    if ((t & 63) == 0) s[t >> 6] = v;
    __syncthreads();
    if (t == 0) bsum[blockIdx.x] = s[0] + s[1] + s[2] + s[3];
}

// stage 2: exclusive scan of block sums (single block, tiles of 256 w/ carry)
__global__ __launch_bounds__(256) void scan_bsums(int* __restrict__ bsum, int NB) {
    __shared__ int s[256];
    __shared__ int carry;
    int t = threadIdx.x;
    if (t == 0) carry = 0;
    __syncthreads();
    for (int base = 0; base < NB; base += 256) {
        int i = base + t;
        int v = (i < NB) ? bsum[i] : 0;
        s[t] = v;
        __syncthreads();
        for (int o = 1; o < 256; o <<= 1) {
            int u = (t >= o) ? s[t - o] : 0;
            __syncthreads();
            s[t] += u;
            __syncthreads();
        }
        int excl = ((t == 0) ? 0 : s[t - 1]) + carry;
        if (i < NB) bsum[i] = excl;
        __syncthreads();
        if (t == 0) carry += s[255];
        __syncthreads();
    }
}

// stage 3: in-block exclusive scan + block offset -> indptr
__global__ __launch_bounds__(256) void scatter_scan(const int* __restrict__ cnt,
                                                    const int* __restrict__ bsum,
                                                    int* __restrict__ indptr, int N) {
    __shared__ int s[256];
    int t = threadIdx.x;
    int i = blockIdx.x * 256 + t;
    int v = (i < N) ? cnt[i] : 0;
    s[t] = v;
    __syncthreads();
    for (int o = 1; o < 256; o <<= 1) {
        int u = (t >= o) ? s[t - o] : 0;
        __syncthreads();
        s[t] += u;
        __syncthreads();
    }
    int excl = ((t == 0) ? 0 : s[t - 1]) + bsum[blockIdx.x];
    if (i < N) indptr[i] = excl;
    if (i == N - 1) indptr[N] = excl + v;
}

// CSR scatter: one block per coarse bucket, cursors in LDS, csr window ~17 KB
__global__ __launch_bounds__(256) void csr_scatter(const int2* __restrict__ part,
                                                   const int* __restrict__ bucketBase,
                                                   const int* __restrict__ indptr,
                                                   int* __restrict__ csr, int N) {
    __shared__ int cur[256];
    int t = threadIdx.x;
    int b = blockIdx.x;
    int d = b * 256 + t;
    cur[t] = (d < N) ? indptr[d] : 0;
    __syncthreads();
    int s0 = bucketBase[b], s1 = bucketBase[b + 1];
    for (int i = s0 + t; i < s1; i += 256) {
        int2 e = part[i];
        int p = atomicAdd(&cur[e.y & 255], 1);
        csr[p] = e.x;
    }
    __syncthreads();
    if (d < N) csr[cur[t]] = d;   // self-loop fills the one remaining slot
}

// ---------------- W split+swizzle into MFMA B-fragment order ----------------
__global__ __launch_bounds__(256) void split_w(const float* __restrict__ W,
                                               ushort_t* __restrict__ Whs,
                                               ushort_t* __restrict__ Wls) {
    int idx = blockIdx.x * 256 + threadIdx.x;   // 0..16383
    int j    = idx & 7;
    int lane = (idx >> 3) & 63;
    int ks   = (idx >> 9) & 3;
    int ct   = idx >> 11;
    int n = ct * 16 + (lane & 15);
    int k = ks * 32 + (lane >> 4) * 8 + j;
    ushort_t hi, lo;
    bsplit(W[k * 128 + n], hi, lo);
    Whs[idx] = hi;
    Wls[idx] = lo;
}

// ---------------- GEMM via split-bf16 MFMA + fused attention logits ----------------
__global__ __launch_bounds__(256) void gemm_mfma(const float* __restrict__ A,
                                                 const ushort_t* __restrict__ Whs,
                                                 const ushort_t* __restrict__ Wls,
                                                 const float* __restrict__ a_s,
                                                 const float* __restrict__ a_d,
                                                 __half* __restrict__ h16,
                                                 float* __restrict__ als,
                                                 float* __restrict__ ald, int N) {
    const int gw   = (blockIdx.x * 256 + threadIdx.x) >> 6;
    const int lane = threadIdx.x & 63;
    const int r0   = gw * 32;
    if (r0 >= N) return;
    const int m = lane & 15;
    const int q = lane >> 4;

    bf16x8 ah[2][4], al[2][4];
    #pragma unroll
    for (int t = 0; t < 2; ++t) {
        int row = r0 + t * 16 + m;
        if (row >= N) row = N - 1;      // safe clamp; stores are guarded
        const float* ap = A + (size_t)row * HD;
        #pragma unroll
        for (int ks = 0; ks < 4; ++ks) {
            float4 v0 = *(const float4*)(ap + ks * 32 + q * 8);
            float4 v1 = *(const float4*)(ap + ks * 32 + q * 8 + 4);
            float vv[8] = {v0.x, v0.y, v0.z, v0.w, v1.x, v1.y, v1.z, v1.w};
            #pragma unroll
            for (int j = 0; j < 8; ++j) {
                ushort_t hb, lb;
                bsplit(vv[j], hb, lb);
                ah[t][ks][j] = (short)hb;
                al[t][ks][j] = (short)lb;
            }
        }
    }

    float ps[2][4] = {{0,0,0,0},{0,0,0,0}};
    float pd[2][4] = {{0,0,0,0},{0,0,0,0}};

    #pragma unroll 1
    for (int ct = 0; ct < 8; ++ct) {
        f32x4 acc0 = {0.f, 0.f, 0.f, 0.f};
        f32x4 acc1 = {0.f, 0.f, 0.f, 0.f};
        #pragma unroll
        for (int ks = 0; ks < 4; ++ks) {
            bf16x8 wh = *(const bf16x8*)(Whs + ((size_t)(ct * 4 + ks) * 64 + lane) * 8);
            bf16x8 wl = *(const bf16x8*)(Wls + ((size_t)(ct * 4 + ks) * 64 + lane) * 8);
            acc0 = __builtin_amdgcn_mfma_f32_16x16x32_bf16(ah[0][ks], wh, acc0, 0, 0, 0);
            acc1 = __builtin_amdgcn_mfma_f32_16x16x32_bf16(ah[1][ks], wh, acc1, 0, 0, 0);
            acc0 = __builtin_amdgcn_mfma_f32_16x16x32_bf16(al[0][ks], wh, acc0, 0, 0, 0);
            acc1 = __builtin_amdgcn_mfma_f32_16x16x32_bf16(al[1][ks], wh, acc1, 0, 0, 0);
            acc0 = __builtin_amdgcn_mfma_f32_16x16x32_bf16(ah[0][ks], wl, acc0, 0, 0, 0);
            acc1 = __builtin_amdgcn_mfma_f32_16x16x32_bf16(ah[1][ks], wl, acc1, 0, 0, 0);
        }
        const int col = ct * 16 + m;
        const float asv = a_s[col], adv = a_d[col];
        #pragma unroll
        for (int reg = 0; reg < 4; ++reg) {
            ps[0][reg] += acc0[reg] * asv;  pd[0][reg] += acc0[reg] * adv;
            ps[1][reg] += acc1[reg] * asv;  pd[1][reg] += acc1[reg] * adv;
            int row0 = r0 + q * 4 + reg;
            if (row0 < N) h16[(size_t)row0 * HD + col] = __float2half(acc0[reg]);
            int row1 = row0 + 16;
            if (row1 < N) h16[(size_t)row1 * HD + col] = __float2half(acc1[reg]);
        }
        if (ct == 3 || ct == 7) {
            int head = ct >> 2;
            #pragma unroll
            for (int t = 0; t < 2; ++t) {
                #pragma unroll
                for (int reg = 0; reg < 4; ++reg) {
                    float vs = ps[t][reg], vd = pd[t][reg];
                    for (int o = 8; o >= 1; o >>= 1) {
                        vs += __shfl_xor(vs, o, 64);
                        vd += __shfl_xor(vd, o, 64);
                    }
                    if (m == 0) {
                        int row = r0 + t * 16 + q * 4 + reg;
                        if (row < N) { als[2 * row + head] = vs; ald[2 * row + head] = vd; }
                    }
                    ps[t][reg] = 0.f;  pd[t][reg] = 0.f;
                }
            }
        }
    }
}

// ---------------- GAT aggregation: one wave per dst node ----------------
__global__ __launch_bounds__(256) void gat_aggregate(const __half* __restrict__ h,
                                                     const float* __restrict__ als,
                                                     const float* __restrict__ ald,
                                                     const int* __restrict__ indptr,
                                                     const int* __restrict__ csr,
                                                     const float* __restrict__ bias,
                                                     float* __restrict__ out,
                                                     const float* __restrict__ Wh,
                                                     float* __restrict__ svec, int N) {
    int w    = (blockIdx.x * blockDim.x + threadIdx.x) >> 6;
    int lane = threadIdx.x & 63;
    if (w >= N) return;
    int start = indptr[w], end = indptr[w + 1];
    float ad0 = ald[2 * w], ad1 = ald[2 * w + 1];
    const bool head0 = (lane < 32);
    const int cbase = lane * 2;

    float accx = 0.f, accy = 0.f, d0 = 0.f, d1 = 0.f;
    for (int base = start; base < end; base += 64) {
        int i = base + lane;
        float w0 = 0.f, w1 = 0.f; int s = 0;
        if (i < end) {
            s = csr[i];
            float2 av = *(const float2*)&als[2 * s];
            float e0 = av.x + ad0;
            float e1 = av.y + ad1;
            e0 = e0 > 0.f ? e0 : NEG_SLOPE * e0;
            e1 = e1 > 0.f ? e1 : NEG_SLOPE * e1;
            w0 = __expf(e0);
            w1 = __expf(e1);
        }
        d0 += w0; d1 += w1;
        int nl = end - base; if (nl > 64) nl = 64;
        int j = 0;
        for (; j + 8 <= nl; j += 8) {
            int sj[8]; float wa[8];
            #pragma unroll
            for (int u = 0; u < 8; ++u) {
                sj[u] = __shfl(s, j + u, 64);
                float a = __shfl(w0, j + u, 64);
                float b = __shfl(w1, j + u, 64);
                wa[u] = head0 ? a : b;
            }
            __half2 hv[8];
            #pragma unroll
            for (int u = 0; u < 8; ++u)
                hv[u] = *(const __half2*)&h[(size_t)sj[u] * HD + cbase];
            #pragma unroll
            for (int u = 0; u < 8; ++u) {
                float2 f = __half22float2(hv[u]);
                accx += wa[u] * f.x;
                accy += wa[u] * f.y;
            }
        }
        for (; j < nl; ++j) {
            int sjv = __shfl(s, j, 64);
            float a = __shfl(w0, j, 64);
            float b = __shfl(w1, j, 64);
            float wj = head0 ? a : b;
            float2 f = __half22float2(*(const __half2*)&h[(size_t)sjv * HD + cbase]);
            accx += wj * f.x;
            accy += wj * f.y;
        }
    }
    for (int o = 32; o >= 1; o >>= 1) {
        d0 += __shfl_xor(d0, o, 64);
        d1 += __shfl_xor(d1, o, 64);
    }
    float D = (head0 ? d0 : d1) + EPSV;
    float ox = accx / D + bias[cbase];
    float oy = accy / D + bias[cbase + 1];
    ox = ox > 0.f ? ox : 0.f;   // ReLU
    oy = oy > 0.f ? oy : 0.f;

    if (svec) {
        float2 wv = *(const float2*)&Wh[cbase];
        float part = ox * wv.x + oy * wv.y;
        for (int o = 32; o >= 1; o >>= 1) part += __shfl_xor(part, o, 64);
        if (lane == 0) svec[w] = part;
    } else {
        *(float2*)&out[(size_t)w * HD + cbase] = make_float2(ox, oy);
    }
}

// ---------------- graph boundaries (batch is sorted) ----------------
__global__ void graph_bounds(const int* __restrict__ batch, int* __restrict__ gstart,
                             int N, int G) {
    int g = blockIdx.x * blockDim.x + threadIdx.x;
    if (g > G) return;
    int lo = 0, hi = N;
    while (lo < hi) {
        int mid = (lo + hi) >> 1;
        if (batch[mid] < g) lo = mid + 1; else hi = mid;
    }
    gstart[g] = lo;
}

// ---------------- per-graph reduce of per-node head dots ----------------
__global__ __launch_bounds__(256) void pool_reduce(const float* __restrict__ s,
                                                   const int* __restrict__ gstart,
                                                   const float* __restrict__ bh,
                                                   float* __restrict__ out, int G) {
    __shared__ float partial[4];
    int g = blockIdx.x, t = threadIdx.x;
    int a = gstart[g], b = gstart[g + 1];
    float sum = 0.f;
    for (int i = a + t; i < b; i += 256) sum += s[i];
    for (int o = 32; o >= 1; o >>= 1) sum += __shfl_xor(sum, o, 64);
    if ((t & 63) == 0) partial[t >> 6] = sum;
    __syncthreads();
    if (t == 0) {
        float cnt = (float)(b - a); if (cnt < 1.f) cnt = 1.f;
        out[g] = (partial[0] + partial[1] + partial[2] + partial[3]) / cnt + bh[0];
    }
}

// ---------------- launch ----------------
extern "C" void kernel_launch(void* const* d_in, const int* in_sizes, int n_in,
                              void* d_out, int out_size, void* d_ws, size_t ws_size,
                              hipStream_t stream) {
    const float* x     = (const float*)d_in[0];
    const int*   ei    = (const int*)d_in[1];
    const int*   batch = (const int*)d_in[2];
    const float* W1  = (const float*)d_in[3];
    const float* as1 = (const float*)d_in[4];
    const float* ad1 = (const float*)d_in[5];
    const float* b1  = (const float*)d_in[6];
    const float* W2  = (const float*)d_in[7];
    const float* as2 = (const float*)d_in[8];
    const float* ad2 = (const float*)d_in[9];
    const float* b2  = (const float*)d_in[10];
    const float* Wh  = (const float*)d_in[11];
    const float* bh  = (const float*)d_in[12];
    float* out = (float*)d_out;

    const int N = in_sizes[0] / HD;
    const int E = in_sizes[1] / 2;
    const int G = out_size;
    const int* srcp = ei;
    const int* dstp = ei + E;
    const int NB  = (N + 255) / 256;      // scan blocks
    const int NBK = (N + 255) / 256;      // coarse buckets (dst>>8)
    const int NT  = (E + TILE - 1) / TILE;

    char* ws = (char*)d_ws;
    size_t off = 0;
    auto alloc = [&](size_t bytes) -> void* {
        void* p = ws + off;
        off += (bytes + 255) & ~(size_t)255;
        return p;
    };
    __half* h16   = (__half*)alloc((size_t)N * HD * 2);
    float* ob     = (float*)alloc((size_t)N * HD * 4);
    float* als    = (float*)alloc((size_t)N * 2 * 4);
    float* ald    = (float*)alloc((size_t)N * 2 * 4);
    float* svec   = (float*)alloc((size_t)N * 4);
    int*   indptr = (int*)  alloc((size_t)(N + 1) * 4);
    int*   cnt    = (int*)  alloc((size_t)N * 4);
    int*   bsum   = (int*)  alloc((size_t)NB * 4);
    int*   csr    = (int*)  alloc((size_t)(E + N) * 4);
    int*   gstart = (int*)  alloc((size_t)(G + 1) * 4);
    int*   tileHist   = (int*)alloc((size_t)NT * 256 * 4);
    int*   bucketBase = (int*)alloc(257 * 4);
    int2*  part   = (int2*) alloc((size_t)E * 8);
    ushort_t* Whs1 = (ushort_t*)alloc(16384 * 2);
    ushort_t* Wls1 = (ushort_t*)alloc(16384 * 2);
    ushort_t* Whs2 = (ushort_t*)alloc(16384 * 2);
    ushort_t* Wls2 = (ushort_t*)alloc(16384 * 2);

    // CSR build: partition by dst>>8, then LDS-cursor scatter per bucket
    part_hist<<<NT, 256, 0, stream>>>(dstp, tileHist, E);
    part_offsets<<<1, 256, 0, stream>>>(tileHist, bucketBase, NT);
    part_scatter<<<NT, 256, 0, stream>>>(srcp, dstp, tileHist, part, E);
    fine_counts<<<NBK, 256, 0, stream>>>(part, bucketBase, cnt, N);
    block_sums<<<NB, 256, 0, stream>>>(cnt, bsum, N);
    scan_bsums<<<1, 256, 0, stream>>>(bsum, NB);
    scatter_scan<<<NB, 256, 0, stream>>>(cnt, bsum, indptr, N);
    csr_scatter<<<NBK, 256, 0, stream>>>(part, bucketBase, indptr, csr, N);
    graph_bounds<<<1, 64, 0, stream>>>(batch, gstart, N, G);

    // W split+swizzle (tiny)
    split_w<<<64, 256, 0, stream>>>(W1, Whs1, Wls1);
    split_w<<<64, 256, 0, stream>>>(W2, Whs2, Wls2);

    const int nwaves  = (N + 31) / 32;
    const int gblocks = (nwaves + 3) / 4;
    int wgrid = (N * 64 + 255) / 256;

    // layer 1 (logits fused into GEMM epilogue; h stored fp16)
    gemm_mfma<<<gblocks, 256, 0, stream>>>(x, Whs1, Wls1, as1, ad1, h16, als, ald, N);
    gat_aggregate<<<wgrid, 256, 0, stream>>>(h16, als, ald, indptr, csr, b1, ob,
                                             nullptr, nullptr, N);
    // layer 2
    gemm_mfma<<<gblocks, 256, 0, stream>>>(ob, Whs2, Wls2, as2, ad2, h16, als, ald, N);
    gat_aggregate<<<wgrid, 256, 0, stream>>>(h16, als, ald, indptr, csr, b2, nullptr,
                                             Wh, svec, N);
    // pool + head (tiny: 50 blocks x ~1000 scalars)
    pool_reduce<<<G, 256, 0, stream>>>(svec, gstart, bh, out, G);
}

// Round 8
// 263.969 us; speedup vs baseline: 2.8212x; 1.0343x over previous
//
#include <hip/hip_runtime.h>
#include <hip/hip_fp16.h>
#include <math.h>

#define HD 128          // hidden dim (= H*C = D_IN)
#define NEG_SLOPE 0.2f
#define EPSV 1e-16f
#define TILE 8192       // edges per partition tile

typedef unsigned short ushort_t;
typedef __attribute__((ext_vector_type(8))) short bf16x8;
typedef __attribute__((ext_vector_type(4))) float f32x4;

// RNE split of fp32 into hi/lo bf16 bit patterns
__device__ inline void bsplit(float x, ushort_t& hi, ushort_t& lo) {
    unsigned u = __float_as_uint(x);
    unsigned hb = (u + 0x7FFFu + ((u >> 16) & 1u)) >> 16;
    hi = (ushort_t)hb;
    float res = x - __uint_as_float(hb << 16);
    unsigned v = __float_as_uint(res);
    lo = (ushort_t)((v + 0x7FFFu + ((v >> 16) & 1u)) >> 16);
}

// ---------------- edge partition by coarse bucket (dst>>8) ----------------
__global__ __launch_bounds__(256) void part_hist(const int* __restrict__ dst,
                                                 int* __restrict__ tileHist, int E) {
    __shared__ int hist[256];
    int t = threadIdx.x;
    hist[t] = 0;
    __syncthreads();
    int base = blockIdx.x * TILE;
    int end = base + TILE; if (end > E) end = E;
    for (int i = base + t; i < end; i += 256)
        atomicAdd(&hist[dst[i] >> 8], 1);
    __syncthreads();
    tileHist[blockIdx.x * 256 + t] = hist[t];
}

__global__ __launch_bounds__(256) void part_offsets(int* __restrict__ tileHist,
                                                    int* __restrict__ bucketBase,
                                                    int NT) {
    __shared__ int s[256];
    int b = threadIdx.x;
    int total = 0;
    #pragma unroll 8
    for (int t = 0; t < NT; ++t) total += tileHist[t * 256 + b];
    s[b] = total;
    __syncthreads();
    for (int o = 1; o < 256; o <<= 1) {
        int v = (b >= o) ? s[b - o] : 0;
        __syncthreads();
        s[b] += v;
        __syncthreads();
    }
    int base = (b == 0) ? 0 : s[b - 1];
    bucketBase[b] = base;
    if (b == 255) bucketBase[256] = s[255];
    int run = base;
    #pragma unroll 8
    for (int t = 0; t < NT; ++t) {
        int v = tileHist[t * 256 + b];
        tileHist[t * 256 + b] = run;
        run += v;
    }
}

__global__ __launch_bounds__(256) void part_scatter(const int* __restrict__ src,
                                                    const int* __restrict__ dst,
                                                    const int* __restrict__ tileHist,
                                                    int2* __restrict__ part, int E) {
    __shared__ int cur[256];
    int t = threadIdx.x;
    cur[t] = tileHist[blockIdx.x * 256 + t];
    __syncthreads();
    int base = blockIdx.x * TILE;
    int end = base + TILE; if (end > E) end = E;
    for (int i = base + t; i < end; i += 256) {
        int d = dst[i], s = src[i];
        int p = atomicAdd(&cur[d >> 8], 1);
        part[p] = make_int2(s, d);
    }
}

// per-node counts from partitioned edges (+1 for self-loop)
__global__ __launch_bounds__(256) void fine_counts(const int2* __restrict__ part,
                                                   const int* __restrict__ bucketBase,
                                                   int* __restrict__ cnt, int N) {
    __shared__ int hist[256];
    int t = threadIdx.x;
    hist[t] = 0;
    __syncthreads();
    int b = blockIdx.x;
    int s0 = bucketBase[b], s1 = bucketBase[b + 1];
    for (int i = s0 + t; i < s1; i += 256)
        atomicAdd(&hist[part[i].y & 255], 1);
    __syncthreads();
    int d = b * 256 + t;
    if (d < N) cnt[d] = hist[t] + 1;
}

// hierarchical scan, stage 1: per-256-chunk sums
__global__ __launch_bounds__(256) void block_sums(const int* __restrict__ cnt,
                                                  int* __restrict__ bsum, int N) {
    __shared__ int s[4];
    int t = threadIdx.x;
    int i = blockIdx.x * 256 + t;
    int v = (i < N) ? cnt[i] : 0;
    for (int o = 32; o >= 1; o >>= 1) v += __shfl_xor(v, o, 64);
    if ((t & 63) == 0) s[t >> 6] = v;
    __syncthreads();
    if (t == 0) bsum[blockIdx.x] = s[0] + s[1] + s[2] + s[3];
}

// stage 2: exclusive scan of block sums (single block, tiles of 256 w/ carry)
__global__ __launch_bounds__(256) void scan_bsums(int* __restrict__ bsum, int NB) {
    __shared__ int s[256];
    __shared__ int carry;
    int t = threadIdx.x;
    if (t == 0) carry = 0;
    __syncthreads();
    for (int base = 0; base < NB; base += 256) {
        int i = base + t;
        int v = (i < NB) ? bsum[i] : 0;
        s[t] = v;
        __syncthreads();
        for (int o = 1; o < 256; o <<= 1) {
            int u = (t >= o) ? s[t - o] : 0;
            __syncthreads();
            s[t] += u;
            __syncthreads();
        }
        int excl = ((t == 0) ? 0 : s[t - 1]) + carry;
        if (i < NB) bsum[i] = excl;
        __syncthreads();
        if (t == 0) carry += s[255];
        __syncthreads();
    }
}

// stage 3: in-block exclusive scan + block offset -> indptr
__global__ __launch_bounds__(256) void scatter_scan(const int* __restrict__ cnt,
                                                    const int* __restrict__ bsum,
                                                    int* __restrict__ indptr, int N) {
    __shared__ int s[256];
    int t = threadIdx.x;
    int i = blockIdx.x * 256 + t;
    int v = (i < N) ? cnt[i] : 0;
    s[t] = v;
    __syncthreads();
    for (int o = 1; o < 256; o <<= 1) {
        int u = (t >= o) ? s[t - o] : 0;
        __syncthreads();
        s[t] += u;
        __syncthreads();
    }
    int excl = ((t == 0) ? 0 : s[t - 1]) + bsum[blockIdx.x];
    if (i < N) indptr[i] = excl;
    if (i == N - 1) indptr[N] = excl + v;
}

// CSR scatter: one block per coarse bucket, cursors in LDS
__global__ __launch_bounds__(256) void csr_scatter(const int2* __restrict__ part,
                                                   const int* __restrict__ bucketBase,
                                                   const int* __restrict__ indptr,
                                                   int* __restrict__ csr, int N) {
    __shared__ int cur[256];
    int t = threadIdx.x;
    int b = blockIdx.x;
    int d = b * 256 + t;
    cur[t] = (d < N) ? indptr[d] : 0;
    __syncthreads();
    int s0 = bucketBase[b], s1 = bucketBase[b + 1];
    for (int i = s0 + t; i < s1; i += 256) {
        int2 e = part[i];
        int p = atomicAdd(&cur[e.y & 255], 1);
        csr[p] = e.x;
    }
    __syncthreads();
    if (d < N) csr[cur[t]] = d;   // self-loop fills the one remaining slot
}

// ---------------- W split+swizzle into MFMA B-fragment order ----------------
__global__ __launch_bounds__(256) void split_w(const float* __restrict__ W,
                                               ushort_t* __restrict__ Whs,
                                               ushort_t* __restrict__ Wls) {
    int idx = blockIdx.x * 256 + threadIdx.x;   // 0..16383
    int j    = idx & 7;
    int lane = (idx >> 3) & 63;
    int ks   = (idx >> 9) & 3;
    int ct   = idx >> 11;
    int n = ct * 16 + (lane & 15);
    int k = ks * 32 + (lane >> 4) * 8 + j;
    ushort_t hi, lo;
    bsplit(W[k * 128 + n], hi, lo);
    Whs[idx] = hi;
    Wls[idx] = lo;
}

// ---------------- A-row 8-element loaders (fp32 or fp16 input) ----------------
__device__ inline void load8(const float* p, float* vv) {
    float4 a = *(const float4*)p;
    float4 b = *(const float4*)(p + 4);
    vv[0]=a.x; vv[1]=a.y; vv[2]=a.z; vv[3]=a.w;
    vv[4]=b.x; vv[5]=b.y; vv[6]=b.z; vv[7]=b.w;
}
__device__ inline void load8(const __half* p, float* vv) {
    bf16x8 r = *(const bf16x8*)p;
    #pragma unroll
    for (int j = 0; j < 8; ++j)
        vv[j] = __half2float(__ushort_as_half((ushort_t)r[j]));
}

// ---------------- GEMM via split-bf16 MFMA + fused attention logits ----------------
// One wave = 16 rows (high occupancy: ~3 blocks/CU). A-frags in regs;
// W-frags L2-resident. h written fp16. Logits via 16-lane xor reductions.
template <typename TA>
__global__ __launch_bounds__(256) void gemm_mfma(const TA* __restrict__ A,
                                                 const ushort_t* __restrict__ Whs,
                                                 const ushort_t* __restrict__ Wls,
                                                 const float* __restrict__ a_s,
                                                 const float* __restrict__ a_d,
                                                 __half* __restrict__ h16,
                                                 float* __restrict__ als,
                                                 float* __restrict__ ald, int N) {
    const int gw   = (blockIdx.x * 256 + threadIdx.x) >> 6;
    const int lane = threadIdx.x & 63;
    const int r0   = gw * 16;
    if (r0 >= N) return;
    const int m = lane & 15;
    const int q = lane >> 4;

    bf16x8 ah[4], al[4];
    {
        int row = r0 + m;
        if (row >= N) row = N - 1;      // safe clamp; stores are guarded
        const TA* ap = A + (size_t)row * HD;
        #pragma unroll
        for (int ks = 0; ks < 4; ++ks) {
            float vv[8];
            load8(ap + ks * 32 + q * 8, vv);
            #pragma unroll
            for (int j = 0; j < 8; ++j) {
                ushort_t hb, lb;
                bsplit(vv[j], hb, lb);
                ah[ks][j] = (short)hb;
                al[ks][j] = (short)lb;
            }
        }
    }

    float ps[4] = {0,0,0,0};
    float pd[4] = {0,0,0,0};

    #pragma unroll 1
    for (int ct = 0; ct < 8; ++ct) {
        f32x4 acc = {0.f, 0.f, 0.f, 0.f};
        #pragma unroll
        for (int ks = 0; ks < 4; ++ks) {
            bf16x8 wh = *(const bf16x8*)(Whs + ((size_t)(ct * 4 + ks) * 64 + lane) * 8);
            bf16x8 wl = *(const bf16x8*)(Wls + ((size_t)(ct * 4 + ks) * 64 + lane) * 8);
            acc = __builtin_amdgcn_mfma_f32_16x16x32_bf16(ah[ks], wh, acc, 0, 0, 0);
            acc = __builtin_amdgcn_mfma_f32_16x16x32_bf16(al[ks], wh, acc, 0, 0, 0);
            acc = __builtin_amdgcn_mfma_f32_16x16x32_bf16(ah[ks], wl, acc, 0, 0, 0);
        }
        const int col = ct * 16 + m;
        const float asv = a_s[col], adv = a_d[col];
        #pragma unroll
        for (int reg = 0; reg < 4; ++reg) {
            ps[reg] += acc[reg] * asv;
            pd[reg] += acc[reg] * adv;
            int row = r0 + q * 4 + reg;
            if (row < N) h16[(size_t)row * HD + col] = __float2half(acc[reg]);
        }
        if (ct == 3 || ct == 7) {          // head boundary: reduce over m-lanes
            int head = ct >> 2;
            #pragma unroll
            for (int reg = 0; reg < 4; ++reg) {
                float vs = ps[reg], vd = pd[reg];
                for (int o = 8; o >= 1; o >>= 1) {
                    vs += __shfl_xor(vs, o, 64);
                    vd += __shfl_xor(vd, o, 64);
                }
                if (m == 0) {
                    int row = r0 + q * 4 + reg;
                    if (row < N) { als[2 * row + head] = vs; ald[2 * row + head] = vd; }
                }
                ps[reg] = 0.f;  pd[reg] = 0.f;
            }
        }
    }
}

// ---------------- GAT aggregation: one wave per dst node ----------------
// Weights packed fp16-pair -> ONE shuffle per edge for weights; zero-weight
// masking removes the scalar tail. Denominator uses the same fp16 weights.
__global__ __launch_bounds__(256) void gat_aggregate(const __half* __restrict__ h,
                                                     const float* __restrict__ als,
                                                     const float* __restrict__ ald,
                                                     const int* __restrict__ indptr,
                                                     const int* __restrict__ csr,
                                                     const float* __restrict__ bias,
                                                     __half* __restrict__ out,
                                                     const float* __restrict__ Wh,
                                                     float* __restrict__ svec, int N) {
    int w    = (blockIdx.x * blockDim.x + threadIdx.x) >> 6;
    int lane = threadIdx.x & 63;
    if (w >= N) return;
    int start = indptr[w], end = indptr[w + 1];
    float ad0 = ald[2 * w], ad1 = ald[2 * w + 1];
    const bool head0 = (lane < 32);
    const int cbase = lane * 2;

    float accx = 0.f, accy = 0.f, d0 = 0.f, d1 = 0.f;
    for (int base = start; base < end; base += 64) {
        int i = base + lane;
        int idx = i < end ? i : end - 1;
        int s = csr[idx];
        unsigned wpack = 0u;
        if (i < end) {
            float2 av = *(const float2*)&als[2 * s];
            float e0 = av.x + ad0;
            float e1 = av.y + ad1;
            e0 = e0 > 0.f ? e0 : NEG_SLOPE * e0;
            e1 = e1 > 0.f ? e1 : NEG_SLOPE * e1;
            __half p0 = __float2half(__expf(e0));
            __half p1 = __float2half(__expf(e1));
            wpack = ((unsigned)__half_as_ushort(p1) << 16) | __half_as_ushort(p0);
            d0 += __half2float(p0);
            d1 += __half2float(p1);
        }
        int nl = end - base; if (nl > 64) nl = 64;
        int nb = (nl + 7) >> 3;
        for (int b = 0; b < nb; ++b) {
            int j = b * 8;
            int sj[8]; float wa[8];
            #pragma unroll
            for (int u = 0; u < 8; ++u) {
                sj[u] = __shfl(s, j + u, 64);
                unsigned wp = (unsigned)__shfl((int)wpack, j + u, 64);
                unsigned bits = head0 ? (wp & 0xffffu) : (wp >> 16);
                wa[u] = __half2float(__ushort_as_half((ushort_t)bits));
            }
            __half2 hv[8];
            #pragma unroll
            for (int u = 0; u < 8; ++u)
                hv[u] = *(const __half2*)&h[(size_t)sj[u] * HD + cbase];
            #pragma unroll
            for (int u = 0; u < 8; ++u) {
                float2 f = __half22float2(hv[u]);
                accx += wa[u] * f.x;
                accy += wa[u] * f.y;
            }
        }
    }
    for (int o = 32; o >= 1; o >>= 1) {
        d0 += __shfl_xor(d0, o, 64);
        d1 += __shfl_xor(d1, o, 64);
    }
    float D = (head0 ? d0 : d1) + EPSV;
    float ox = accx / D + bias[cbase];
    float oy = accy / D + bias[cbase + 1];
    ox = ox > 0.f ? ox : 0.f;   // ReLU
    oy = oy > 0.f ? oy : 0.f;

    if (svec) {
        float2 wv = *(const float2*)&Wh[cbase];
        float part = ox * wv.x + oy * wv.y;
        for (int o = 32; o >= 1; o >>= 1) part += __shfl_xor(part, o, 64);
        if (lane == 0) svec[w] = part;
    } else {
        *(__half2*)&out[(size_t)w * HD + cbase] =
            __halves2half2(__float2half(ox), __float2half(oy));
    }
}

// ---------------- graph boundaries (batch is sorted) ----------------
__global__ void graph_bounds(const int* __restrict__ batch, int* __restrict__ gstart,
                             int N, int G) {
    int g = blockIdx.x * blockDim.x + threadIdx.x;
    if (g > G) return;
    int lo = 0, hi = N;
    while (lo < hi) {
        int mid = (lo + hi) >> 1;
        if (batch[mid] < g) lo = mid + 1; else hi = mid;
    }
    gstart[g] = lo;
}

// ---------------- per-graph reduce of per-node head dots ----------------
__global__ __launch_bounds__(256) void pool_reduce(const float* __restrict__ s,
                                                   const int* __restrict__ gstart,
                                                   const float* __restrict__ bh,
                                                   float* __restrict__ out, int G) {
    __shared__ float partial[4];
    int g = blockIdx.x, t = threadIdx.x;
    int a = gstart[g], b = gstart[g + 1];
    float sum = 0.f;
    for (int i = a + t; i < b; i += 256) sum += s[i];
    for (int o = 32; o >= 1; o >>= 1) sum += __shfl_xor(sum, o, 64);
    if ((t & 63) == 0) partial[t >> 6] = sum;
    __syncthreads();
    if (t == 0) {
        float cnt = (float)(b - a); if (cnt < 1.f) cnt = 1.f;
        out[g] = (partial[0] + partial[1] + partial[2] + partial[3]) / cnt + bh[0];
    }
}

// ---------------- launch ----------------
extern "C" void kernel_launch(void* const* d_in, const int* in_sizes, int n_in,
                              void* d_out, int out_size, void* d_ws, size_t ws_size,
                              hipStream_t stream) {
    const float* x     = (const float*)d_in[0];
    const int*   ei    = (const int*)d_in[1];
    const int*   batch = (const int*)d_in[2];
    const float* W1  = (const float*)d_in[3];
    const float* as1 = (const float*)d_in[4];
    const float* ad1 = (const float*)d_in[5];
    const float* b1  = (const float*)d_in[6];
    const float* W2  = (const float*)d_in[7];
    const float* as2 = (const float*)d_in[8];
    const float* ad2 = (const float*)d_in[9];
    const float* b2  = (const float*)d_in[10];
    const float* Wh  = (const float*)d_in[11];
    const float* bh  = (const float*)d_in[12];
    float* out = (float*)d_out;

    const int N = in_sizes[0] / HD;
    const int E = in_sizes[1] / 2;
    const int G = out_size;
    const int* srcp = ei;
    const int* dstp = ei + E;
    const int NB  = (N + 255) / 256;      // scan blocks
    const int NBK = (N + 255) / 256;      // coarse buckets (dst>>8)
    const int NT  = (E + TILE - 1) / TILE;

    char* ws = (char*)d_ws;
    size_t off = 0;
    auto alloc = [&](size_t bytes) -> void* {
        void* p = ws + off;
        off += (bytes + 255) & ~(size_t)255;
        return p;
    };
    __half* h16   = (__half*)alloc((size_t)N * HD * 2);
    __half* ob16  = (__half*)alloc((size_t)N * HD * 2);
    float* als    = (float*)alloc((size_t)N * 2 * 4);
    float* ald    = (float*)alloc((size_t)N * 2 * 4);
    float* svec   = (float*)alloc((size_t)N * 4);
    int*   indptr = (int*)  alloc((size_t)(N + 1) * 4);
    int*   cnt    = (int*)  alloc((size_t)N * 4);
    int*   bsum   = (int*)  alloc((size_t)NB * 4);
    int*   csr    = (int*)  alloc((size_t)(E + N) * 4);
    int*   gstart = (int*)  alloc((size_t)(G + 1) * 4);
    int*   tileHist   = (int*)alloc((size_t)NT * 256 * 4);
    int*   bucketBase = (int*)alloc(257 * 4);
    int2*  part   = (int2*) alloc((size_t)E * 8);
    ushort_t* Whs1 = (ushort_t*)alloc(16384 * 2);
    ushort_t* Wls1 = (ushort_t*)alloc(16384 * 2);
    ushort_t* Whs2 = (ushort_t*)alloc(16384 * 2);
    ushort_t* Wls2 = (ushort_t*)alloc(16384 * 2);

    // CSR build: partition by dst>>8, then LDS-cursor scatter per bucket
    part_hist<<<NT, 256, 0, stream>>>(dstp, tileHist, E);
    part_offsets<<<1, 256, 0, stream>>>(tileHist, bucketBase, NT);
    part_scatter<<<NT, 256, 0, stream>>>(srcp, dstp, tileHist, part, E);
    fine_counts<<<NBK, 256, 0, stream>>>(part, bucketBase, cnt, N);
    block_sums<<<NB, 256, 0, stream>>>(cnt, bsum, N);
    scan_bsums<<<1, 256, 0, stream>>>(bsum, NB);
    scatter_scan<<<NB, 256, 0, stream>>>(cnt, bsum, indptr, N);
    csr_scatter<<<NBK, 256, 0, stream>>>(part, bucketBase, indptr, csr, N);
    graph_bounds<<<1, 64, 0, stream>>>(batch, gstart, N, G);

    // W split+swizzle (tiny)
    split_w<<<64, 256, 0, stream>>>(W1, Whs1, Wls1);
    split_w<<<64, 256, 0, stream>>>(W2, Whs2, Wls2);

    const int nwaves  = (N + 15) / 16;
    const int gblocks = (nwaves + 3) / 4;
    int wgrid = (N * 64 + 255) / 256;

    // layer 1 (logits fused into GEMM epilogue; h stored fp16)
    gemm_mfma<<<gblocks, 256, 0, stream>>>(x, Whs1, Wls1, as1, ad1, h16, als, ald, N);
    gat_aggregate<<<wgrid, 256, 0, stream>>>(h16, als, ald, indptr, csr, b1, ob16,
                                             nullptr, nullptr, N);
    // layer 2 (input fp16)
    gemm_mfma<<<gblocks, 256, 0, stream>>>(ob16, Whs2, Wls2, as2, ad2, h16, als, ald, N);
    gat_aggregate<<<wgrid, 256, 0, stream>>>(h16, als, ald, indptr, csr, b2, nullptr,
                                             Wh, svec, N);
    // pool + head (tiny: 50 blocks x ~1000 scalars)
    pool_reduce<<<G, 256, 0, stream>>>(svec, gstart, bh, out, G);
}